// Round 3
// baseline (7303.846 us; speedup 1.0000x reference)
//
#include <hip/hip_runtime.h>
#include <stdint.h>

#define TT 2048
#define DD 2048
#define HH 16
#define HDIM 128
#define NE 8
#define TOPK 2
#define FF 1408
#define FSS 5632
#define NL 2

typedef __bf16 bf16;
typedef __bf16 bf16x2 __attribute__((ext_vector_type(2)));
typedef __bf16 bf16x4 __attribute__((ext_vector_type(4)));
typedef __bf16 bf16x8 __attribute__((ext_vector_type(8)));
typedef float f32x4 __attribute__((ext_vector_type(4)));

__device__ __forceinline__ void split1(float f, bf16& h, bf16& l) {
  bf16 hb = (bf16)f;
  h = hb;
  l = (bf16)(f - (float)hb);
}

#define BM 128
#define BN 128
#define BK 64
#define BKP 72

// ---------------------------------------------------- bf16 GEMM (layer-2 moe)
// C[M,N] = A_bf16[M,K] @ B_f32[K,N] (B converted to bf16 at staging).
// OM: 0 = bf16 out, 1 = f32 out.
template<bool EXPERT, bool GATHER, int OM>
__launch_bounds__(256, 2)
__global__ void k_gemm(const bf16* __restrict__ A, const float* __restrict__ B,
                       void* __restrict__ Cv, int M, int N, int Kd, int lda, int ldc,
                       const int* __restrict__ perm, const int* __restrict__ cnt,
                       const int* __restrict__ ofs)
{
  int m_count = M, row_base = 0;
  const float* Bp = B;
  if (EXPERT) {
    int e = blockIdx.z;
    m_count = cnt[e];
    if ((int)(blockIdx.x * BM) >= m_count) return;
    row_base = ofs[e];
    Bp += (size_t)e * (size_t)Kd * (size_t)N;
  }
  const int tid = threadIdx.x;
  const int lane = tid & 63;
  const int wid = tid >> 6;
  const int wm = (wid >> 1) * 64, wn = (wid & 1) * 64;
  const int lr = lane & 15, g = lane >> 4;
  const int n0 = blockIdx.y * BN;

  __shared__ bf16 As[BM][BKP];
  __shared__ bf16 Bs[BN][BKP];

  const bf16* asrc[4];
  int s_row[4], s_kc[4];
#pragma unroll
  for (int it = 0; it < 4; ++it) {
    int c = tid + it * 256;
    int r = c >> 3, kc = c & 7;
    s_row[it] = r; s_kc[it] = kc;
    int lrow = blockIdx.x * BM + r;
    int tok;
    if (EXPERT) {
      bool v = lrow < m_count;
      if (GATHER) tok = v ? perm[row_base + lrow] : 0;
      else        tok = v ? (row_base + lrow) : row_base;
    } else {
      tok = lrow;
    }
    asrc[it] = A + (size_t)tok * lda + kc * 8;
  }

  f32x4 acc[4][4];
#pragma unroll
  for (int i = 0; i < 4; ++i)
#pragma unroll
    for (int j = 0; j < 4; ++j)
      acc[i][j] = (f32x4){0.f, 0.f, 0.f, 0.f};

  for (int k0 = 0; k0 < Kd; k0 += BK) {
#pragma unroll
    for (int it = 0; it < 4; ++it) {
      uint4 d = *(const uint4*)(asrc[it] + k0);
      *(uint4*)&As[s_row[it]][s_kc[it] * 8] = d;
    }
#pragma unroll
    for (int it = 0; it < 4; ++it) {
      int c = tid + it * 256;
      int kp = c >> 5, nc = c & 31;
      const float* b0 = Bp + (size_t)(k0 + kp * 2) * N + n0 + nc * 4;
      float4 fa = *(const float4*)b0;
      float4 fb = *(const float4*)(b0 + N);
      int nn = nc * 4;
      *(bf16x2*)&Bs[nn + 0][kp * 2] = (bf16x2){(bf16)fa.x, (bf16)fb.x};
      *(bf16x2*)&Bs[nn + 1][kp * 2] = (bf16x2){(bf16)fa.y, (bf16)fb.y};
      *(bf16x2*)&Bs[nn + 2][kp * 2] = (bf16x2){(bf16)fa.z, (bf16)fb.z};
      *(bf16x2*)&Bs[nn + 3][kp * 2] = (bf16x2){(bf16)fa.w, (bf16)fb.w};
    }
    __syncthreads();
#pragma unroll
    for (int kk = 0; kk < 2; ++kk) {
      bf16x8 af[4], bfp[4];
#pragma unroll
      for (int i = 0; i < 4; ++i)
        af[i] = *(const bf16x8*)&As[wm + i * 16 + lr][kk * 32 + g * 8];
#pragma unroll
      for (int j = 0; j < 4; ++j)
        bfp[j] = *(const bf16x8*)&Bs[wn + j * 16 + lr][kk * 32 + g * 8];
#pragma unroll
      for (int i = 0; i < 4; ++i)
#pragma unroll
        for (int j = 0; j < 4; ++j)
          acc[i][j] = __builtin_amdgcn_mfma_f32_16x16x32_bf16(af[i], bfp[j], acc[i][j], 0, 0, 0);
    }
    __syncthreads();
  }

  const int r0 = g * 4;
#pragma unroll
  for (int i = 0; i < 4; ++i) {
    int lrow0 = blockIdx.x * BM + wm + i * 16 + r0;
#pragma unroll
    for (int j = 0; j < 4; ++j) {
      int col = n0 + wn + j * 16 + lr;
#pragma unroll
      for (int r = 0; r < 4; ++r) {
        int lrow = lrow0 + r;
        if (EXPERT && lrow >= m_count) continue;
        size_t off = (size_t)(row_base + lrow) * ldc + col;
        if (OM == 0) ((bf16*)Cv)[off] = (bf16)acc[i][j][r];
        else         ((float*)Cv)[off] = acc[i][j][r];
      }
    }
  }
}

// ------------------------------------------- split-precision GEMM (4-term) ---
// C[M,N] = A_f32[M,K] @ B_f32[K,N], both split to bf16 hi+lo at staging;
// 4 MFMA per fragment pair => ~f32-accurate result.
// OM: 1 = f32 out, 3 = bf16 hi/lo pair out (row-major), 4 = pair transposed.
template<bool EXPERT, bool GATHER, int OM>
__launch_bounds__(256, 2)
__global__ void k_gemms(const float* __restrict__ A, const float* __restrict__ B,
                        void* __restrict__ C1, void* __restrict__ C2,
                        int M, int N, int Kd, int lda, int ldc,
                        const int* __restrict__ perm, const int* __restrict__ cnt,
                        const int* __restrict__ ofs)
{
  int m_count = M, row_base = 0;
  const float* Bp = B;
  if (EXPERT) {
    int e = blockIdx.z;
    m_count = cnt[e];
    if ((int)(blockIdx.x * BM) >= m_count) return;
    row_base = ofs[e];
    Bp += (size_t)e * (size_t)Kd * (size_t)N;
  }
  const int tid = threadIdx.x;
  const int lane = tid & 63;
  const int wid = tid >> 6;
  const int wm = (wid >> 1) * 64, wn = (wid & 1) * 64;
  const int lr = lane & 15, g = lane >> 4;
  const int n0 = blockIdx.y * BN;

  __shared__ bf16 Ah[BM][BKP];
  __shared__ bf16 Al[BM][BKP];
  __shared__ bf16 Bh[BN][BKP];
  __shared__ bf16 Bl[BN][BKP];

  const float* asrc[4];
  int s_row[4], s_kc[4];
#pragma unroll
  for (int it = 0; it < 4; ++it) {
    int c = tid + it * 256;
    int r = c >> 3, kc = c & 7;
    s_row[it] = r; s_kc[it] = kc;
    int lrow = blockIdx.x * BM + r;
    int tok;
    if (EXPERT) {
      bool v = lrow < m_count;
      if (GATHER) tok = v ? perm[row_base + lrow] : 0;
      else        tok = v ? (row_base + lrow) : row_base;
    } else {
      tok = lrow;
    }
    asrc[it] = A + (size_t)tok * lda + kc * 8;
  }

  f32x4 acc[4][4];
#pragma unroll
  for (int i = 0; i < 4; ++i)
#pragma unroll
    for (int j = 0; j < 4; ++j)
      acc[i][j] = (f32x4){0.f, 0.f, 0.f, 0.f};

  for (int k0 = 0; k0 < Kd; k0 += BK) {
#pragma unroll
    for (int it = 0; it < 4; ++it) {
      const float* s = asrc[it] + k0;
      float4 fa = *(const float4*)s;
      float4 fb = *(const float4*)(s + 4);
      float v[8] = {fa.x, fa.y, fa.z, fa.w, fb.x, fb.y, fb.z, fb.w};
      bf16x8 hv, lv;
#pragma unroll
      for (int j = 0; j < 8; ++j) { bf16 hb, lb; split1(v[j], hb, lb); hv[j] = hb; lv[j] = lb; }
      *(bf16x8*)&Ah[s_row[it]][s_kc[it] * 8] = hv;
      *(bf16x8*)&Al[s_row[it]][s_kc[it] * 8] = lv;
    }
#pragma unroll
    for (int it = 0; it < 4; ++it) {
      int c = tid + it * 256;
      int kp = c >> 5, nc = c & 31;
      const float* b0 = Bp + (size_t)(k0 + kp * 2) * N + n0 + nc * 4;
      float4 fa = *(const float4*)b0;
      float4 fb = *(const float4*)(b0 + N);
      float va[4] = {fa.x, fa.y, fa.z, fa.w};
      float vb[4] = {fb.x, fb.y, fb.z, fb.w};
      int nn = nc * 4;
#pragma unroll
      for (int i = 0; i < 4; ++i) {
        bf16 h0, l0, h1, l1;
        split1(va[i], h0, l0);
        split1(vb[i], h1, l1);
        *(bf16x2*)&Bh[nn + i][kp * 2] = (bf16x2){h0, h1};
        *(bf16x2*)&Bl[nn + i][kp * 2] = (bf16x2){l0, l1};
      }
    }
    __syncthreads();
#pragma unroll
    for (int kk = 0; kk < 2; ++kk) {
      bf16x8 afh[4], afl[4], bfh[4], bfl[4];
#pragma unroll
      for (int i = 0; i < 4; ++i) {
        afh[i] = *(const bf16x8*)&Ah[wm + i * 16 + lr][kk * 32 + g * 8];
        afl[i] = *(const bf16x8*)&Al[wm + i * 16 + lr][kk * 32 + g * 8];
      }
#pragma unroll
      for (int j = 0; j < 4; ++j) {
        bfh[j] = *(const bf16x8*)&Bh[wn + j * 16 + lr][kk * 32 + g * 8];
        bfl[j] = *(const bf16x8*)&Bl[wn + j * 16 + lr][kk * 32 + g * 8];
      }
#pragma unroll
      for (int i = 0; i < 4; ++i)
#pragma unroll
        for (int j = 0; j < 4; ++j) {
          f32x4 t = acc[i][j];
          t = __builtin_amdgcn_mfma_f32_16x16x32_bf16(afh[i], bfh[j], t, 0, 0, 0);
          t = __builtin_amdgcn_mfma_f32_16x16x32_bf16(afh[i], bfl[j], t, 0, 0, 0);
          t = __builtin_amdgcn_mfma_f32_16x16x32_bf16(afl[i], bfh[j], t, 0, 0, 0);
          t = __builtin_amdgcn_mfma_f32_16x16x32_bf16(afl[i], bfl[j], t, 0, 0, 0);
          acc[i][j] = t;
        }
    }
    __syncthreads();
  }

  const int r0 = g * 4;
#pragma unroll
  for (int i = 0; i < 4; ++i) {
    int lrow0 = blockIdx.x * BM + wm + i * 16 + r0;
#pragma unroll
    for (int j = 0; j < 4; ++j) {
      int col = n0 + wn + j * 16 + lr;
      if (OM == 4) {
        bf16x4 ph, pl;
#pragma unroll
        for (int r = 0; r < 4; ++r) { bf16 hb, lb; split1(acc[i][j][r], hb, lb); ph[r] = hb; pl[r] = lb; }
        *(bf16x4*)&((bf16*)C1)[(size_t)col * ldc + lrow0] = ph;
        *(bf16x4*)&((bf16*)C2)[(size_t)col * ldc + lrow0] = pl;
      } else {
#pragma unroll
        for (int r = 0; r < 4; ++r) {
          int lrow = lrow0 + r;
          if (EXPERT && lrow >= m_count) continue;
          size_t off = (size_t)(row_base + lrow) * ldc + col;
          if (OM == 1) {
            ((float*)C1)[off] = acc[i][j][r];
          } else {  // OM == 3
            bf16 hb, lb; split1(acc[i][j][r], hb, lb);
            ((bf16*)C1)[off] = hb;
            ((bf16*)C2)[off] = lb;
          }
        }
      }
    }
  }
}

// ------------------------------------ split-precision flash attention -------
// One wave = 16 q rows; block = 4 waves; grid (T/64, H).
// Q,K as hi/lo bf16 pairs [T][D]; V as hi/lo transposed [D][T]; out f32 [T][D].
__launch_bounds__(256)
__global__ void k_attns(const bf16* __restrict__ Qh, const bf16* __restrict__ Ql,
                        const bf16* __restrict__ Kh, const bf16* __restrict__ Kl,
                        const bf16* __restrict__ Vh, const bf16* __restrict__ Vl,
                        float* __restrict__ Of)
{
  const int lane = threadIdx.x & 63, wid = threadIdx.x >> 6;
  const int head = blockIdx.y;
  const int qbase = blockIdx.x * 64 + wid * 16;
  const int lr = lane & 15, g = lane >> 4;
  __shared__ bf16 pl_h[4][16][40];
  __shared__ bf16 pl_l[4][16][40];

  bf16x8 qfh[4], qfl[4];
  {
    size_t qoff = (size_t)(qbase + lr) * DD + head * HDIM;
#pragma unroll
    for (int c = 0; c < 4; ++c) {
      qfh[c] = *(const bf16x8*)(Qh + qoff + c * 32 + g * 8);
      qfl[c] = *(const bf16x8*)(Ql + qoff + c * 32 + g * 8);
    }
  }

  f32x4 o[8];
#pragma unroll
  for (int d = 0; d < 8; ++d) o[d] = (f32x4){0.f, 0.f, 0.f, 0.f};
  float m_r[4] = {-1e30f, -1e30f, -1e30f, -1e30f};
  float l_r[4] = {0.f, 0.f, 0.f, 0.f};

  for (int kb = 0; kb < qbase + 16; kb += 32) {
    f32x4 s0 = {0.f,0.f,0.f,0.f}, s1 = {0.f,0.f,0.f,0.f};
    size_t k0off = (size_t)(kb + lr) * DD + head * HDIM;
    size_t k1off = k0off + (size_t)16 * DD;
#pragma unroll
    for (int c = 0; c < 4; ++c) {
      bf16x8 kh = *(const bf16x8*)(Kh + k0off + c * 32 + g * 8);
      bf16x8 kl = *(const bf16x8*)(Kl + k0off + c * 32 + g * 8);
      s0 = __builtin_amdgcn_mfma_f32_16x16x32_bf16(qfh[c], kh, s0, 0, 0, 0);
      s0 = __builtin_amdgcn_mfma_f32_16x16x32_bf16(qfh[c], kl, s0, 0, 0, 0);
      s0 = __builtin_amdgcn_mfma_f32_16x16x32_bf16(qfl[c], kh, s0, 0, 0, 0);
      s0 = __builtin_amdgcn_mfma_f32_16x16x32_bf16(qfl[c], kl, s0, 0, 0, 0);
    }
#pragma unroll
    for (int c = 0; c < 4; ++c) {
      bf16x8 kh = *(const bf16x8*)(Kh + k1off + c * 32 + g * 8);
      bf16x8 kl = *(const bf16x8*)(Kl + k1off + c * 32 + g * 8);
      s1 = __builtin_amdgcn_mfma_f32_16x16x32_bf16(qfh[c], kh, s1, 0, 0, 0);
      s1 = __builtin_amdgcn_mfma_f32_16x16x32_bf16(qfh[c], kl, s1, 0, 0, 0);
      s1 = __builtin_amdgcn_mfma_f32_16x16x32_bf16(qfl[c], kh, s1, 0, 0, 0);
      s1 = __builtin_amdgcn_mfma_f32_16x16x32_bf16(qfl[c], kl, s1, 0, 0, 0);
    }
    float p0[4], p1[4], mx[4], alpha[4];
#pragma unroll
    for (int r = 0; r < 4; ++r) {
      int q = qbase + g * 4 + r;
      float a0 = s0[r] * 0.08838834764831845f;
      float a1 = s1[r] * 0.08838834764831845f;
      if (kb + lr > q)      a0 = -1e30f;
      if (kb + 16 + lr > q) a1 = -1e30f;
      p0[r] = a0; p1[r] = a1;
      mx[r] = fmaxf(a0, a1);
    }
#pragma unroll
    for (int off = 1; off < 16; off <<= 1)
#pragma unroll
      for (int r = 0; r < 4; ++r) mx[r] = fmaxf(mx[r], __shfl_xor(mx[r], off, 64));
#pragma unroll
    for (int r = 0; r < 4; ++r) {
      float mn = fmaxf(m_r[r], mx[r]);
      alpha[r] = __expf(m_r[r] - mn);
      m_r[r] = mn;
      p0[r] = __expf(p0[r] - mn);
      p1[r] = __expf(p1[r] - mn);
    }
    float ps[4];
#pragma unroll
    for (int r = 0; r < 4; ++r) ps[r] = p0[r] + p1[r];
#pragma unroll
    for (int off = 1; off < 16; off <<= 1)
#pragma unroll
      for (int r = 0; r < 4; ++r) ps[r] += __shfl_xor(ps[r], off, 64);
#pragma unroll
    for (int r = 0; r < 4; ++r) l_r[r] = l_r[r] * alpha[r] + ps[r];
#pragma unroll
    for (int d = 0; d < 8; ++d)
#pragma unroll
      for (int r = 0; r < 4; ++r) o[d][r] *= alpha[r];
#pragma unroll
    for (int r = 0; r < 4; ++r) {
      bf16 hb, lb;
      split1(p0[r], hb, lb);
      pl_h[wid][g * 4 + r][lr] = hb;
      pl_l[wid][g * 4 + r][lr] = lb;
      split1(p1[r], hb, lb);
      pl_h[wid][g * 4 + r][16 + lr] = hb;
      pl_l[wid][g * 4 + r][16 + lr] = lb;
    }
    bf16x8 pah = *(const bf16x8*)&pl_h[wid][lr][g * 8];
    bf16x8 pal = *(const bf16x8*)&pl_l[wid][lr][g * 8];
#pragma unroll
    for (int d = 0; d < 8; ++d) {
      size_t voff = (size_t)(head * HDIM + d * 16 + lr) * TT + kb + g * 8;
      bf16x8 vfh = *(const bf16x8*)(Vh + voff);
      bf16x8 vfl = *(const bf16x8*)(Vl + voff);
      o[d] = __builtin_amdgcn_mfma_f32_16x16x32_bf16(pah, vfh, o[d], 0, 0, 0);
      o[d] = __builtin_amdgcn_mfma_f32_16x16x32_bf16(pah, vfl, o[d], 0, 0, 0);
      o[d] = __builtin_amdgcn_mfma_f32_16x16x32_bf16(pal, vfh, o[d], 0, 0, 0);
      o[d] = __builtin_amdgcn_mfma_f32_16x16x32_bf16(pal, vfl, o[d], 0, 0, 0);
    }
  }
#pragma unroll
  for (int r = 0; r < 4; ++r) l_r[r] = 1.f / l_r[r];
  float* orow = Of + head * HDIM;
#pragma unroll
  for (int d = 0; d < 8; ++d)
#pragma unroll
    for (int r = 0; r < 4; ++r)
      orow[(size_t)(qbase + g * 4 + r) * DD + d * 16 + lr] = o[d][r] * l_r[r];
}

// ------------------------------------------------------------- helpers ------
__global__ void k_embed(const int* __restrict__ ids, const float* __restrict__ Em,
                        float* __restrict__ Hout)
{
  int t = blockIdx.x, tid = threadIdx.x;
  const float4* s = (const float4*)(Em + (size_t)ids[t] * DD);
  float4* dst = (float4*)(Hout + (size_t)t * DD);
  dst[tid] = s[tid];
  dst[tid + 256] = s[tid + 256];
}

template<bool ADDIN, bool WF32, bool FINAL>
__launch_bounds__(256)
__global__ void k_addrms(const float* __restrict__ Hin, float* __restrict__ Res,
                         const float* __restrict__ W,
                         bf16* __restrict__ Xb, float* __restrict__ Xf)
{
  const int t = blockIdx.x, tid = threadIdx.x;
  const size_t base = (size_t)t * DD + tid * 8;
  float x[8];
  {
    const float4* hp = (const float4*)(Hin + base);
    float4 a = hp[0], b = hp[1];
    x[0]=a.x; x[1]=a.y; x[2]=a.z; x[3]=a.w;
    x[4]=b.x; x[5]=b.y; x[6]=b.z; x[7]=b.w;
    if (ADDIN) {
      const float4* rp = (const float4*)(Res + base);
      float4 c = rp[0], d = rp[1];
      x[0]+=c.x; x[1]+=c.y; x[2]+=c.z; x[3]+=c.w;
      x[4]+=d.x; x[5]+=d.y; x[6]+=d.z; x[7]+=d.w;
    }
  }
  {
    float4* rp = (float4*)(Res + base);
    rp[0] = make_float4(x[0], x[1], x[2], x[3]);
    rp[1] = make_float4(x[4], x[5], x[6], x[7]);
  }
  float ss = 0.f;
#pragma unroll
  for (int j = 0; j < 8; ++j) ss += x[j] * x[j];
#pragma unroll
  for (int off = 32; off; off >>= 1) ss += __shfl_xor(ss, off, 64);
  __shared__ float red[4];
  if ((tid & 63) == 0) red[tid >> 6] = ss;
  __syncthreads();
  float tot = red[0] + red[1] + red[2] + red[3];
  float sc = rsqrtf(tot * (1.0f / DD) + 1e-6f);
  float y[8];
#pragma unroll
  for (int j = 0; j < 8; ++j) y[j] = x[j] * sc * W[tid * 8 + j];
  if (!FINAL) {
    union { bf16 b[8]; uint4 u; } pk;
#pragma unroll
    for (int j = 0; j < 8; ++j) pk.b[j] = (bf16)y[j];
    *(uint4*)(Xb + base) = pk.u;
  }
  if (WF32 || FINAL) {
    float4* xp = (float4*)(Xf + base);
    xp[0] = make_float4(y[0], y[1], y[2], y[3]);
    xp[1] = make_float4(y[4], y[5], y[6], y[7]);
  }
}

// RoPE on split hi/lo Q,K with double-precision angle/trig (matches np f64 ref).
__global__ void k_rope2(bf16* __restrict__ Qh, bf16* __restrict__ Ql,
                        bf16* __restrict__ Kh, bf16* __restrict__ Kl,
                        const int* __restrict__ pos)
{
  int idx = blockIdx.x * 256 + threadIdx.x;
  int d = idx & 63;
  int h = (idx >> 6) & (HH - 1);
  int t = idx >> 10;
  if (t >= TT) return;
  double inv = pow(1.0e6, -(double)d / 64.0);
  double ang = (double)pos[t] * inv;
  double sd, cd;
  sincos(ang, &sd, &cd);
  float sn = (float)sd, cs = (float)cd;
  size_t base = (size_t)t * DD + h * HDIM + d;
  float q1 = (float)Qh[base] + (float)Ql[base];
  float q2 = (float)Qh[base + 64] + (float)Ql[base + 64];
  float qa = q1 * cs - q2 * sn, qb = q1 * sn + q2 * cs;
  bf16 hb, lb;
  split1(qa, hb, lb); Qh[base] = hb;      Ql[base] = lb;
  split1(qb, hb, lb); Qh[base + 64] = hb; Ql[base + 64] = lb;
  float k1 = (float)Kh[base] + (float)Kl[base];
  float k2 = (float)Kh[base + 64] + (float)Kl[base + 64];
  float ka = k1 * cs - k2 * sn, kb2 = k1 * sn + k2 * cs;
  split1(ka, hb, lb);  Kh[base] = hb;      Kl[base] = lb;
  split1(kb2, hb, lb); Kh[base + 64] = hb; Kl[base + 64] = lb;
}

__launch_bounds__(64)
__global__ void k_router(const float* __restrict__ Xf, const float* __restrict__ RW,
                         const float* __restrict__ SGW, int* __restrict__ eidx,
                         float* __restrict__ ew, float* __restrict__ sgate,
                         int* __restrict__ cnt)
{
  const int t = blockIdx.x, lane = threadIdx.x;
  const float* x = Xf + (size_t)t * DD;
  float acc[8] = {0,0,0,0,0,0,0,0};
  float sg = 0.f;
  for (int i = lane; i < DD; i += 64) {
    float xv = x[i];
    const float4* w = (const float4*)(RW + (size_t)i * NE);
    float4 w0 = w[0], w1 = w[1];
    acc[0] += xv * w0.x; acc[1] += xv * w0.y; acc[2] += xv * w0.z; acc[3] += xv * w0.w;
    acc[4] += xv * w1.x; acc[5] += xv * w1.y; acc[6] += xv * w1.z; acc[7] += xv * w1.w;
    sg += xv * SGW[i];
  }
#pragma unroll
  for (int off = 32; off; off >>= 1) {
#pragma unroll
    for (int e = 0; e < 8; ++e) acc[e] += __shfl_xor(acc[e], off, 64);
    sg += __shfl_xor(sg, off, 64);
  }
  if (lane == 0) {
    // top-2 on raw logits (exp is monotone; avoids exp rounding noise)
    int i0 = 0; float v0 = acc[0];
    for (int e = 1; e < 8; ++e) if (acc[e] > v0) { v0 = acc[e]; i0 = e; }
    int i1 = -1; float v1 = -1e30f;
    for (int e = 0; e < 8; ++e) if (e != i0 && acc[e] > v1) { v1 = acc[e]; i1 = e; }
    float w0 = 1.f / (1.f + expf(v1 - v0));   // = p0/(p0+p1)
    eidx[2*t] = i0; eidx[2*t+1] = i1;
    ew[2*t] = w0; ew[2*t+1] = 1.f - w0;
    sgate[t] = 1.f / (1.f + expf(-sg));
    atomicAdd(&cnt[i0], 1);
    atomicAdd(&cnt[i1], 1);
  }
}

__global__ void k_scan(const int* __restrict__ cnt, int* __restrict__ ofs)
{
  if (threadIdx.x == 0) {
    int s = 0;
    for (int e = 0; e < NE; ++e) { ofs[e] = s; s += cnt[e]; }
    ofs[NE] = s;
  }
}

__global__ void k_assign(const int* __restrict__ eidx, const int* __restrict__ ofs,
                         int* __restrict__ cursor, int* __restrict__ perm,
                         int* __restrict__ posof)
{
  int t = blockIdx.x * 256 + threadIdx.x;
  if (t >= TT) return;
#pragma unroll
  for (int j = 0; j < 2; ++j) {
    int e = eidx[2*t + j];
    int p = ofs[e] + atomicAdd(&cursor[e], 1);
    perm[p] = t;
    posof[2*t + j] = p;
  }
}

__global__ void k_silumul(bf16* __restrict__ G, const bf16* __restrict__ U, int n)
{
  int i = (blockIdx.x * 256 + threadIdx.x) * 8;
  if (i >= n) return;
  bf16x8 gv = *(const bf16x8*)(G + i);
  bf16x8 uv = *(const bf16x8*)(U + i);
  bf16x8 r;
#pragma unroll
  for (int j = 0; j < 8; ++j) {
    float gg = (float)gv[j];
    float uu = (float)uv[j];
    float s = gg / (1.f + expf(-gg));
    r[j] = (bf16)(s * uu);
  }
  *(bf16x8*)(G + i) = r;
}

__global__ void k_silumul_f(float* __restrict__ G, const float* __restrict__ U, int n)
{
  int i = (blockIdx.x * 256 + threadIdx.x) * 4;
  if (i >= n) return;
  float4 g = *(const float4*)(G + i);
  float4 u = *(const float4*)(U + i);
  float4 r;
  r.x = g.x / (1.f + expf(-g.x)) * u.x;
  r.y = g.y / (1.f + expf(-g.y)) * u.y;
  r.z = g.z / (1.f + expf(-g.z)) * u.z;
  r.w = g.w / (1.f + expf(-g.w)) * u.w;
  *(float4*)(G + i) = r;
}

template<bool YF32>
__global__ void k_combine(const void* __restrict__ Yv, const float* __restrict__ SH,
                          const float* __restrict__ sgate, const float* __restrict__ ew,
                          const int* __restrict__ posof, float* __restrict__ Hout)
{
  int t = blockIdx.x, tid = threadIdx.x;
  int p0 = posof[2*t], p1 = posof[2*t+1];
  float w0 = ew[2*t], w1 = ew[2*t+1];
  float sgv = sgate[t];
  int d0 = tid * 8;
  float y0[8], y1[8];
  if (YF32) {
    const float* Y = (const float*)Yv;
    const float4* a = (const float4*)(Y + (size_t)p0 * DD + d0);
    const float4* b = (const float4*)(Y + (size_t)p1 * DD + d0);
    float4 a0 = a[0], a1 = a[1], b0 = b[0], b1 = b[1];
    y0[0]=a0.x; y0[1]=a0.y; y0[2]=a0.z; y0[3]=a0.w; y0[4]=a1.x; y0[5]=a1.y; y0[6]=a1.z; y0[7]=a1.w;
    y1[0]=b0.x; y1[1]=b0.y; y1[2]=b0.z; y1[3]=b0.w; y1[4]=b1.x; y1[5]=b1.y; y1[6]=b1.z; y1[7]=b1.w;
  } else {
    const bf16* Y = (const bf16*)Yv;
    bf16x8 a = *(const bf16x8*)(Y + (size_t)p0 * DD + d0);
    bf16x8 b = *(const bf16x8*)(Y + (size_t)p1 * DD + d0);
#pragma unroll
    for (int j = 0; j < 8; ++j) { y0[j] = (float)a[j]; y1[j] = (float)b[j]; }
  }
  const float4* shp = (const float4*)(SH + (size_t)t * DD + d0);
  float4 sa = shp[0], sb = shp[1];
  float shv[8] = {sa.x, sa.y, sa.z, sa.w, sb.x, sb.y, sb.z, sb.w};
  float out[8];
#pragma unroll
  for (int j = 0; j < 8; ++j)
    out[j] = (y0[j] * w0 + y1[j] * w1 + sgv * shv[j]) * 0.70710678118654752f;
  float4* op = (float4*)(Hout + (size_t)t * DD + d0);
  op[0] = make_float4(out[0], out[1], out[2], out[3]);
  op[1] = make_float4(out[4], out[5], out[6], out[7]);
}

// -------------------------------------------------------------- driver ------
extern "C" void kernel_launch(void* const* d_in, const int* in_sizes, int n_in,
                              void* d_out, int out_size, void* d_ws, size_t ws_size,
                              hipStream_t stream)
{
  (void)in_sizes; (void)n_in; (void)out_size; (void)ws_size;
  const int*   ids  = (const int*)d_in[0];
  const int*   pos  = (const int*)d_in[1];
  const float* emb  = (const float*)d_in[2];
  const float* qw   = (const float*)d_in[3];
  const float* kw   = (const float*)d_in[4];
  const float* vw   = (const float*)d_in[5];
  const float* ow   = (const float*)d_in[6];
  const float* ln1  = (const float*)d_in[7];
  const float* ln2  = (const float*)d_in[8];
  const float* rw   = (const float*)d_in[9];
  const float* sgw  = (const float*)d_in[10];
  const float* wg   = (const float*)d_in[11];
  const float* wu   = (const float*)d_in[12];
  const float* wd   = (const float*)d_in[13];
  const float* swg  = (const float*)d_in[14];
  const float* swu  = (const float*)d_in[15];
  const float* swd  = (const float*)d_in[16];
  const float* fln  = (const float*)d_in[17];

  char* p = (char*)d_ws;
  auto alloc = [&](size_t b) { char* r = p; p += (b + 255) & ~(size_t)255; return r; };

  const size_t TD = (size_t)TT * DD;
  float* resid = (float*)alloc(TD * 4);
  float* hbuf  = (float*)alloc(TD * 4);
  float* xf    = (float*)alloc(TD * 4);
  bf16*  xb    = (bf16*) alloc(TD * 2);
  bf16*  qhb   = (bf16*) alloc(TD * 2);
  bf16*  qlb   = (bf16*) alloc(TD * 2);
  bf16*  khb   = (bf16*) alloc(TD * 2);
  bf16*  klb   = (bf16*) alloc(TD * 2);
  bf16*  vth   = (bf16*) alloc(TD * 2);
  bf16*  vtl   = (bf16*) alloc(TD * 2);
  float* shb   = (float*)alloc(TD * 4);
  int*   eidx  = (int*)  alloc((size_t)TT * TOPK * 4);
  float* ewb   = (float*)alloc((size_t)TT * TOPK * 4);
  float* sgate = (float*)alloc((size_t)TT * 4);
  int*   perm  = (int*)  alloc((size_t)TT * TOPK * 4);
  int*   posof = (int*)  alloc((size_t)TT * TOPK * 4);
  int*   cnt   = (int*)  alloc(64);
  int*   ofs   = (int*)  alloc(64);
  int*   cursor = cnt + 8;

  // Overlaid scratch region (sequentially reused; see lifetime notes):
  const size_t SGF = (size_t)TT * FSS;        // shared-expert intermediate elems
  const size_t GEF = (size_t)TT * TOPK * FF;  // routed-expert intermediate elems
  char* region = alloc(2 * SGF * 4 + 2 * GEF * 4 + (size_t)TT * TOPK * DD * 4);
  // attention output (dead before MoE writes begin each layer)
  float* aof  = (float*)region;
  // layer-0 split (f32) MoE buffers
  float* sgbf = (float*)region;
  float* subf = sgbf + SGF;
  float* gebf = subf + SGF;
  float* uebf = gebf + GEF;
  float* ybf  = uebf + GEF;
  // layer-1 bf16 MoE buffers (same region, later lifetime)
  bf16* sgb = (bf16*)region;
  bf16* sub = sgb + SGF;
  bf16* geb = sub + SGF;
  bf16* ueb = geb + GEF;
  bf16* yb  = ueb + GEF;

  k_embed<<<TT, 256, 0, stream>>>(ids, emb, hbuf);

  for (int l = 0; l < NL; ++l) {
    const float* qw_l  = qw  + (size_t)l * DD * DD;
    const float* kw_l  = kw  + (size_t)l * DD * DD;
    const float* vw_l  = vw  + (size_t)l * DD * DD;
    const float* ow_l  = ow  + (size_t)l * DD * DD;
    const float* ln1_l = ln1 + (size_t)l * DD;
    const float* ln2_l = ln2 + (size_t)l * DD;
    const float* rw_l  = rw  + (size_t)l * DD * NE;
    const float* sgw_l = sgw + (size_t)l * DD;
    const float* wg_l  = wg  + (size_t)l * NE * DD * FF;
    const float* wu_l  = wu  + (size_t)l * NE * DD * FF;
    const float* wd_l  = wd  + (size_t)l * NE * FF * DD;
    const float* swg_l = swg + (size_t)l * DD * FSS;
    const float* swu_l = swu + (size_t)l * DD * FSS;
    const float* swd_l = swd + (size_t)l * FSS * DD;

    if (l == 0)
      k_addrms<false,true,false><<<TT,256,0,stream>>>(hbuf, resid, ln1_l, xb, xf);
    else
      k_addrms<true, true,false><<<TT,256,0,stream>>>(hbuf, resid, ln1_l, xb, xf);

    // QKV (split-precision), V transposed for PV
    k_gemms<false,false,3><<<dim3(16,16),256,0,stream>>>(xf, qw_l, qhb, qlb, TT, DD, DD, DD, DD, nullptr,nullptr,nullptr);
    k_gemms<false,false,3><<<dim3(16,16),256,0,stream>>>(xf, kw_l, khb, klb, TT, DD, DD, DD, DD, nullptr,nullptr,nullptr);
    k_gemms<false,false,4><<<dim3(16,16),256,0,stream>>>(xf, vw_l, vth, vtl, TT, DD, DD, DD, TT, nullptr,nullptr,nullptr);
    k_rope2<<<(TT*HH*64)/256, 256, 0, stream>>>(qhb, qlb, khb, klb, pos);
    k_attns<<<dim3(TT/64, HH), 256, 0, stream>>>(qhb, qlb, khb, klb, vth, vtl, aof);
    k_gemms<false,false,1><<<dim3(16,16),256,0,stream>>>(aof, ow_l, hbuf, nullptr, TT, DD, DD, DD, DD, nullptr,nullptr,nullptr);

    k_addrms<true,true,false><<<TT,256,0,stream>>>(hbuf, resid, ln2_l, xb, xf);

    hipMemsetAsync(cnt, 0, 64, stream);
    k_router<<<TT, 64, 0, stream>>>(xf, rw_l, sgw_l, eidx, ewb, sgate, cnt);
    k_scan<<<1, 64, 0, stream>>>(cnt, ofs);
    k_assign<<<TT/256, 256, 0, stream>>>(eidx, ofs, cursor, perm, posof);

    if (l < NL - 1) {
      // split-precision MoE (feeds next layer's router)
      k_gemms<false,false,1><<<dim3(16,FSS/BN),256,0,stream>>>(xf, swg_l, sgbf, nullptr, TT, FSS, DD, DD, FSS, nullptr,nullptr,nullptr);
      k_gemms<false,false,1><<<dim3(16,FSS/BN),256,0,stream>>>(xf, swu_l, subf, nullptr, TT, FSS, DD, DD, FSS, nullptr,nullptr,nullptr);
      k_silumul_f<<<(TT*FSS/4)/256, 256, 0, stream>>>(sgbf, subf, TT*FSS);
      k_gemms<false,false,1><<<dim3(16,16),256,0,stream>>>(sgbf, swd_l, shb, nullptr, TT, DD, FSS, FSS, DD, nullptr,nullptr,nullptr);

      k_gemms<true,true,1><<<dim3(16,FF/BN,NE),256,0,stream>>>(xf, wg_l, gebf, nullptr, TT, FF, DD, DD, FF, perm, cnt, ofs);
      k_gemms<true,true,1><<<dim3(16,FF/BN,NE),256,0,stream>>>(xf, wu_l, uebf, nullptr, TT, FF, DD, DD, FF, perm, cnt, ofs);
      k_silumul_f<<<(TT*TOPK*FF/4)/256, 256, 0, stream>>>(gebf, uebf, TT*TOPK*FF);
      k_gemms<true,false,1><<<dim3(16,16,NE),256,0,stream>>>(gebf, wd_l, ybf, nullptr, TT, DD, FF, FF, DD, nullptr, cnt, ofs);
      k_combine<true><<<TT, 256, 0, stream>>>(ybf, shb, sgate, ewb, posof, hbuf);
    } else {
      // last layer: plain bf16 MoE (feeds only the value-tolerant output)
      k_gemm<false,false,0><<<dim3(16,FSS/BN),256,0,stream>>>(xb, swg_l, sgb, TT, FSS, DD, DD, FSS, nullptr,nullptr,nullptr);
      k_gemm<false,false,0><<<dim3(16,FSS/BN),256,0,stream>>>(xb, swu_l, sub, TT, FSS, DD, DD, FSS, nullptr,nullptr,nullptr);
      k_silumul<<<(TT*FSS/8)/256, 256, 0, stream>>>(sgb, sub, TT*FSS);
      k_gemm<false,false,1><<<dim3(16,16),256,0,stream>>>(sgb, swd_l, shb, TT, DD, FSS, FSS, DD, nullptr,nullptr,nullptr);

      k_gemm<true,true,0><<<dim3(16,FF/BN,NE),256,0,stream>>>(xb, wg_l, geb, TT, FF, DD, DD, FF, perm, cnt, ofs);
      k_gemm<true,true,0><<<dim3(16,FF/BN,NE),256,0,stream>>>(xb, wu_l, ueb, TT, FF, DD, DD, FF, perm, cnt, ofs);
      k_silumul<<<(TT*TOPK*FF/8)/256, 256, 0, stream>>>(geb, ueb, TT*TOPK*FF);
      k_gemm<true,false,0><<<dim3(16,16,NE),256,0,stream>>>(geb, wd_l, yb, TT, DD, FF, FF, DD, nullptr, cnt, ofs);
      k_combine<false><<<TT, 256, 0, stream>>>(yb, shb, sgate, ewb, posof, hbuf);
    }
  }

  k_addrms<true,false,true><<<TT,256,0,stream>>>(hbuf, resid, fln, nullptr, (float*)d_out);
}

// Round 4
// 6397.560 us; speedup vs baseline: 1.1417x; 1.1417x over previous
//
#include <hip/hip_runtime.h>
#include <stdint.h>

#define TT 2048
#define DD 2048
#define HH 16
#define HDIM 128
#define NE 8
#define TOPK 2
#define FF 1408
#define FSS 5632
#define NL 2

typedef __bf16 bf16;
typedef __bf16 bf16x2 __attribute__((ext_vector_type(2)));
typedef __bf16 bf16x4 __attribute__((ext_vector_type(4)));
typedef __bf16 bf16x8 __attribute__((ext_vector_type(8)));
typedef float f32x4 __attribute__((ext_vector_type(4)));

__device__ __forceinline__ void split1(float f, bf16& h, bf16& l) {
  bf16 hb = (bf16)f;
  h = hb;
  l = (bf16)(f - (float)hb);
}

// ---------------------------------------------------- bf16 GEMM (layer-2 moe)
#define BM 128
#define BN 128
#define BK 64
#define BKP 72

template<bool EXPERT, bool GATHER, int OM>
__launch_bounds__(256, 2)
__global__ void k_gemm(const bf16* __restrict__ A, const float* __restrict__ B,
                       void* __restrict__ Cv, int M, int N, int Kd, int lda, int ldc,
                       const int* __restrict__ perm, const int* __restrict__ cnt,
                       const int* __restrict__ ofs)
{
  int m_count = M, row_base = 0;
  const float* Bp = B;
  if (EXPERT) {
    int e = blockIdx.z;
    m_count = cnt[e];
    if ((int)(blockIdx.x * BM) >= m_count) return;
    row_base = ofs[e];
    Bp += (size_t)e * (size_t)Kd * (size_t)N;
  }
  const int tid = threadIdx.x;
  const int lane = tid & 63;
  const int wid = tid >> 6;
  const int wm = (wid >> 1) * 64, wn = (wid & 1) * 64;
  const int lr = lane & 15, g = lane >> 4;
  const int n0 = blockIdx.y * BN;

  __shared__ bf16 As[BM][BKP];
  __shared__ bf16 Bs[BN][BKP];

  const bf16* asrc[4];
  int s_row[4], s_kc[4];
#pragma unroll
  for (int it = 0; it < 4; ++it) {
    int c = tid + it * 256;
    int r = c >> 3, kc = c & 7;
    s_row[it] = r; s_kc[it] = kc;
    int lrow = blockIdx.x * BM + r;
    int tok;
    if (EXPERT) {
      bool v = lrow < m_count;
      if (GATHER) tok = v ? perm[row_base + lrow] : 0;
      else        tok = v ? (row_base + lrow) : row_base;
    } else {
      tok = lrow;
    }
    asrc[it] = A + (size_t)tok * lda + kc * 8;
  }

  f32x4 acc[4][4];
#pragma unroll
  for (int i = 0; i < 4; ++i)
#pragma unroll
    for (int j = 0; j < 4; ++j)
      acc[i][j] = (f32x4){0.f, 0.f, 0.f, 0.f};

  for (int k0 = 0; k0 < Kd; k0 += BK) {
#pragma unroll
    for (int it = 0; it < 4; ++it) {
      uint4 d = *(const uint4*)(asrc[it] + k0);
      *(uint4*)&As[s_row[it]][s_kc[it] * 8] = d;
    }
#pragma unroll
    for (int it = 0; it < 4; ++it) {
      int c = tid + it * 256;
      int kp = c >> 5, nc = c & 31;
      const float* b0 = Bp + (size_t)(k0 + kp * 2) * N + n0 + nc * 4;
      float4 fa = *(const float4*)b0;
      float4 fb = *(const float4*)(b0 + N);
      int nn = nc * 4;
      *(bf16x2*)&Bs[nn + 0][kp * 2] = (bf16x2){(bf16)fa.x, (bf16)fb.x};
      *(bf16x2*)&Bs[nn + 1][kp * 2] = (bf16x2){(bf16)fa.y, (bf16)fb.y};
      *(bf16x2*)&Bs[nn + 2][kp * 2] = (bf16x2){(bf16)fa.z, (bf16)fb.z};
      *(bf16x2*)&Bs[nn + 3][kp * 2] = (bf16x2){(bf16)fa.w, (bf16)fb.w};
    }
    __syncthreads();
#pragma unroll
    for (int kk = 0; kk < 2; ++kk) {
      bf16x8 af[4], bfp[4];
#pragma unroll
      for (int i = 0; i < 4; ++i)
        af[i] = *(const bf16x8*)&As[wm + i * 16 + lr][kk * 32 + g * 8];
#pragma unroll
      for (int j = 0; j < 4; ++j)
        bfp[j] = *(const bf16x8*)&Bs[wn + j * 16 + lr][kk * 32 + g * 8];
#pragma unroll
      for (int i = 0; i < 4; ++i)
#pragma unroll
        for (int j = 0; j < 4; ++j)
          acc[i][j] = __builtin_amdgcn_mfma_f32_16x16x32_bf16(af[i], bfp[j], acc[i][j], 0, 0, 0);
    }
    __syncthreads();
  }

  const int r0 = g * 4;
#pragma unroll
  for (int i = 0; i < 4; ++i) {
    int lrow0 = blockIdx.x * BM + wm + i * 16 + r0;
#pragma unroll
    for (int j = 0; j < 4; ++j) {
      int col = n0 + wn + j * 16 + lr;
#pragma unroll
      for (int r = 0; r < 4; ++r) {
        int lrow = lrow0 + r;
        if (EXPERT && lrow >= m_count) continue;
        size_t off = (size_t)(row_base + lrow) * ldc + col;
        if (OM == 0) ((bf16*)Cv)[off] = (bf16)acc[i][j][r];
        else         ((float*)Cv)[off] = acc[i][j][r];
      }
    }
  }
}

// ------------------------------------------- split-precision GEMM (3-term) ---
// C[M,N] = A_f32[M,K] @ B_f32[K,N], split to bf16 hi+lo at staging; 3 MFMA
// (hh, hl, lh) per fragment pair => ~f32-accurate. BK=32, register prefetch.
// OM: 1 = f32 out, 3 = bf16 hi/lo pair out, 4 = pair transposed.
template<int BMT, int BNT, bool EXPERT, bool GATHER, int OM>
__launch_bounds__(256, (BNT == 128 ? 3 : 4))
__global__ void k_gemms(const float* __restrict__ A, const float* __restrict__ B,
                        void* __restrict__ C1, void* __restrict__ C2,
                        int M, int N, int Kd, int lda, int ldc,
                        const int* __restrict__ perm, const int* __restrict__ cnt,
                        const int* __restrict__ ofs)
{
  constexpr int ITSA = BMT / 64;   // A: chunks of 8 floats per thread
  constexpr int ITSB = BNT / 64;   // B: paired-row float4s per thread
  constexpr int IF = BMT / 32, JF = BNT / 32;
  constexpr int NCG = BNT / 4;     // B col groups of 4

  int m_count = M, row_base = 0;
  const float* Bp = B;
  if (EXPERT) {
    int e = blockIdx.z;
    m_count = cnt[e];
    if ((int)(blockIdx.x * BMT) >= m_count) return;
    row_base = ofs[e];
    Bp += (size_t)e * (size_t)Kd * (size_t)N;
  }
  const int tid = threadIdx.x;
  const int lane = tid & 63;
  const int wid = tid >> 6;
  const int wm = (wid >> 1) * (BMT / 2), wn = (wid & 1) * (BNT / 2);
  const int lr = lane & 15, g = lane >> 4;
  const int n0 = blockIdx.y * BNT;

  __shared__ bf16 Ah[BMT][40];
  __shared__ bf16 Al[BMT][40];
  __shared__ bf16 Bh[BNT][40];
  __shared__ bf16 Bl[BNT][40];

  const float* asrc[ITSA];
  int s_row[ITSA], s_kc[ITSA];
#pragma unroll
  for (int it = 0; it < ITSA; ++it) {
    int c = tid + it * 256;
    int r = c >> 2, kc = c & 3;   // BK=32: 4 chunks of 8 per row
    s_row[it] = r; s_kc[it] = kc;
    int lrow = blockIdx.x * BMT + r;
    int tok;
    if (EXPERT) {
      bool v = lrow < m_count;
      if (GATHER) tok = v ? perm[row_base + lrow] : 0;
      else        tok = v ? (row_base + lrow) : row_base;
    } else {
      tok = lrow;
    }
    asrc[it] = A + (size_t)tok * lda + kc * 8;
  }
  const float* bsrc[ITSB];
  int b_nn[ITSB], b_kp2[ITSB];
#pragma unroll
  for (int it = 0; it < ITSB; ++it) {
    int c = tid + it * 256;
    int kp = c / NCG, nc = c % NCG;
    b_nn[it] = nc * 4; b_kp2[it] = kp * 2;
    bsrc[it] = Bp + (size_t)(kp * 2) * N + n0 + nc * 4;
  }

  f32x4 acc[IF][JF];
#pragma unroll
  for (int i = 0; i < IF; ++i)
#pragma unroll
    for (int j = 0; j < JF; ++j)
      acc[i][j] = (f32x4){0.f, 0.f, 0.f, 0.f};

  f32x4 aP[ITSA * 2], bP[ITSB * 2];
  auto LD = [&](int k0) {
#pragma unroll
    for (int it = 0; it < ITSA; ++it) {
      const float* s = asrc[it] + k0;
      aP[2 * it]     = *(const f32x4*)s;
      aP[2 * it + 1] = *(const f32x4*)(s + 4);
    }
#pragma unroll
    for (int it = 0; it < ITSB; ++it) {
      const float* s = bsrc[it] + (size_t)k0 * N;
      bP[2 * it]     = *(const f32x4*)s;
      bP[2 * it + 1] = *(const f32x4*)(s + N);
    }
  };

  const int NT = Kd >> 5;
  LD(0);
  for (int t = 0; t < NT; ++t) {
    if (t) __syncthreads();
    // convert + write LDS (consumes prefetch regs)
#pragma unroll
    for (int it = 0; it < ITSA; ++it) {
      bf16x8 hv, lv;
#pragma unroll
      for (int j = 0; j < 8; ++j) {
        bf16 hb, lb;
        split1(aP[2 * it + (j >> 2)][j & 3], hb, lb);
        hv[j] = hb; lv[j] = lb;
      }
      *(bf16x8*)&Ah[s_row[it]][s_kc[it] * 8] = hv;
      *(bf16x8*)&Al[s_row[it]][s_kc[it] * 8] = lv;
    }
#pragma unroll
    for (int it = 0; it < ITSB; ++it) {
      f32x4 fa = bP[2 * it], fb = bP[2 * it + 1];
      int nn = b_nn[it], kp2 = b_kp2[it];
#pragma unroll
      for (int i = 0; i < 4; ++i) {
        bf16 h0, l0, h1, l1;
        split1(fa[i], h0, l0);
        split1(fb[i], h1, l1);
        *(bf16x2*)&Bh[nn + i][kp2] = (bf16x2){h0, h1};
        *(bf16x2*)&Bl[nn + i][kp2] = (bf16x2){l0, l1};
      }
    }
    __syncthreads();
    if (t + 1 < NT) LD((t + 1) << 5);   // issue next tile early (T14)
    // fragment reads + 3-term MFMA
    {
      bf16x8 bh[JF], bl[JF];
#pragma unroll
      for (int j = 0; j < JF; ++j) {
        bh[j] = *(const bf16x8*)&Bh[wn + j * 16 + lr][g * 8];
        bl[j] = *(const bf16x8*)&Bl[wn + j * 16 + lr][g * 8];
      }
#pragma unroll
      for (int i = 0; i < IF; ++i) {
        bf16x8 ah = *(const bf16x8*)&Ah[wm + i * 16 + lr][g * 8];
        bf16x8 al = *(const bf16x8*)&Al[wm + i * 16 + lr][g * 8];
#pragma unroll
        for (int j = 0; j < JF; ++j) {
          f32x4 tacc = acc[i][j];
          tacc = __builtin_amdgcn_mfma_f32_16x16x32_bf16(ah, bh[j], tacc, 0, 0, 0);
          tacc = __builtin_amdgcn_mfma_f32_16x16x32_bf16(ah, bl[j], tacc, 0, 0, 0);
          tacc = __builtin_amdgcn_mfma_f32_16x16x32_bf16(al, bh[j], tacc, 0, 0, 0);
          acc[i][j] = tacc;
        }
      }
    }
  }

  const int r0 = g * 4;
#pragma unroll
  for (int i = 0; i < IF; ++i) {
    int lrow0 = blockIdx.x * BMT + wm + i * 16 + r0;
#pragma unroll
    for (int j = 0; j < JF; ++j) {
      int col = n0 + wn + j * 16 + lr;
      if (OM == 4) {
        bf16x4 ph, pl;
#pragma unroll
        for (int r = 0; r < 4; ++r) { bf16 hb, lb; split1(acc[i][j][r], hb, lb); ph[r] = hb; pl[r] = lb; }
        *(bf16x4*)&((bf16*)C1)[(size_t)col * ldc + lrow0] = ph;
        *(bf16x4*)&((bf16*)C2)[(size_t)col * ldc + lrow0] = pl;
      } else {
#pragma unroll
        for (int r = 0; r < 4; ++r) {
          int lrow = lrow0 + r;
          if (EXPERT && lrow >= m_count) continue;
          size_t off = (size_t)(row_base + lrow) * ldc + col;
          if (OM == 1) {
            ((float*)C1)[off] = acc[i][j][r];
          } else {  // OM == 3
            bf16 hb, lb; split1(acc[i][j][r], hb, lb);
            ((bf16*)C1)[off] = hb;
            ((bf16*)C2)[off] = lb;
          }
        }
      }
    }
  }
}

// ------------------------------------ split-precision flash attention -------
__launch_bounds__(256)
__global__ void k_attns(const bf16* __restrict__ Qh, const bf16* __restrict__ Ql,
                        const bf16* __restrict__ Kh, const bf16* __restrict__ Kl,
                        const bf16* __restrict__ Vh, const bf16* __restrict__ Vl,
                        float* __restrict__ Of)
{
  const int lane = threadIdx.x & 63, wid = threadIdx.x >> 6;
  const int head = blockIdx.y;
  const int qbase = blockIdx.x * 64 + wid * 16;
  const int lr = lane & 15, g = lane >> 4;
  __shared__ bf16 pl_h[4][16][40];
  __shared__ bf16 pl_l[4][16][40];

  bf16x8 qfh[4], qfl[4];
  {
    size_t qoff = (size_t)(qbase + lr) * DD + head * HDIM;
#pragma unroll
    for (int c = 0; c < 4; ++c) {
      qfh[c] = *(const bf16x8*)(Qh + qoff + c * 32 + g * 8);
      qfl[c] = *(const bf16x8*)(Ql + qoff + c * 32 + g * 8);
    }
  }

  f32x4 o[8];
#pragma unroll
  for (int d = 0; d < 8; ++d) o[d] = (f32x4){0.f, 0.f, 0.f, 0.f};
  float m_r[4] = {-1e30f, -1e30f, -1e30f, -1e30f};
  float l_r[4] = {0.f, 0.f, 0.f, 0.f};

  for (int kb = 0; kb < qbase + 16; kb += 32) {
    f32x4 s0 = {0.f,0.f,0.f,0.f}, s1 = {0.f,0.f,0.f,0.f};
    size_t k0off = (size_t)(kb + lr) * DD + head * HDIM;
    size_t k1off = k0off + (size_t)16 * DD;
#pragma unroll
    for (int c = 0; c < 4; ++c) {
      bf16x8 kh = *(const bf16x8*)(Kh + k0off + c * 32 + g * 8);
      bf16x8 kl = *(const bf16x8*)(Kl + k0off + c * 32 + g * 8);
      s0 = __builtin_amdgcn_mfma_f32_16x16x32_bf16(qfh[c], kh, s0, 0, 0, 0);
      s0 = __builtin_amdgcn_mfma_f32_16x16x32_bf16(qfh[c], kl, s0, 0, 0, 0);
      s0 = __builtin_amdgcn_mfma_f32_16x16x32_bf16(qfl[c], kh, s0, 0, 0, 0);
    }
#pragma unroll
    for (int c = 0; c < 4; ++c) {
      bf16x8 kh = *(const bf16x8*)(Kh + k1off + c * 32 + g * 8);
      bf16x8 kl = *(const bf16x8*)(Kl + k1off + c * 32 + g * 8);
      s1 = __builtin_amdgcn_mfma_f32_16x16x32_bf16(qfh[c], kh, s1, 0, 0, 0);
      s1 = __builtin_amdgcn_mfma_f32_16x16x32_bf16(qfh[c], kl, s1, 0, 0, 0);
      s1 = __builtin_amdgcn_mfma_f32_16x16x32_bf16(qfl[c], kh, s1, 0, 0, 0);
    }
    float p0[4], p1[4], mx[4], alpha[4];
#pragma unroll
    for (int r = 0; r < 4; ++r) {
      int q = qbase + g * 4 + r;
      float a0 = s0[r] * 0.08838834764831845f;
      float a1 = s1[r] * 0.08838834764831845f;
      if (kb + lr > q)      a0 = -1e30f;
      if (kb + 16 + lr > q) a1 = -1e30f;
      p0[r] = a0; p1[r] = a1;
      mx[r] = fmaxf(a0, a1);
    }
#pragma unroll
    for (int off = 1; off < 16; off <<= 1)
#pragma unroll
      for (int r = 0; r < 4; ++r) mx[r] = fmaxf(mx[r], __shfl_xor(mx[r], off, 64));
#pragma unroll
    for (int r = 0; r < 4; ++r) {
      float mn = fmaxf(m_r[r], mx[r]);
      alpha[r] = __expf(m_r[r] - mn);
      m_r[r] = mn;
      p0[r] = __expf(p0[r] - mn);
      p1[r] = __expf(p1[r] - mn);
    }
    float ps[4];
#pragma unroll
    for (int r = 0; r < 4; ++r) ps[r] = p0[r] + p1[r];
#pragma unroll
    for (int off = 1; off < 16; off <<= 1)
#pragma unroll
      for (int r = 0; r < 4; ++r) ps[r] += __shfl_xor(ps[r], off, 64);
#pragma unroll
    for (int r = 0; r < 4; ++r) l_r[r] = l_r[r] * alpha[r] + ps[r];
#pragma unroll
    for (int d = 0; d < 8; ++d)
#pragma unroll
      for (int r = 0; r < 4; ++r) o[d][r] *= alpha[r];
#pragma unroll
    for (int r = 0; r < 4; ++r) {
      bf16 hb, lb;
      split1(p0[r], hb, lb);
      pl_h[wid][g * 4 + r][lr] = hb;
      pl_l[wid][g * 4 + r][lr] = lb;
      split1(p1[r], hb, lb);
      pl_h[wid][g * 4 + r][16 + lr] = hb;
      pl_l[wid][g * 4 + r][16 + lr] = lb;
    }
    bf16x8 pah = *(const bf16x8*)&pl_h[wid][lr][g * 8];
    bf16x8 pal = *(const bf16x8*)&pl_l[wid][lr][g * 8];
#pragma unroll
    for (int d = 0; d < 8; ++d) {
      size_t voff = (size_t)(head * HDIM + d * 16 + lr) * TT + kb + g * 8;
      bf16x8 vfh = *(const bf16x8*)(Vh + voff);
      bf16x8 vfl = *(const bf16x8*)(Vl + voff);
      o[d] = __builtin_amdgcn_mfma_f32_16x16x32_bf16(pah, vfh, o[d], 0, 0, 0);
      o[d] = __builtin_amdgcn_mfma_f32_16x16x32_bf16(pah, vfl, o[d], 0, 0, 0);
      o[d] = __builtin_amdgcn_mfma_f32_16x16x32_bf16(pal, vfh, o[d], 0, 0, 0);
    }
  }
#pragma unroll
  for (int r = 0; r < 4; ++r) l_r[r] = 1.f / l_r[r];
  float* orow = Of + head * HDIM;
#pragma unroll
  for (int d = 0; d < 8; ++d)
#pragma unroll
    for (int r = 0; r < 4; ++r)
      orow[(size_t)(qbase + g * 4 + r) * DD + d * 16 + lr] = o[d][r] * l_r[r];
}

// ------------------------------------------------------------- helpers ------
__global__ void k_embed(const int* __restrict__ ids, const float* __restrict__ Em,
                        float* __restrict__ Hout)
{
  int t = blockIdx.x, tid = threadIdx.x;
  const float4* s = (const float4*)(Em + (size_t)ids[t] * DD);
  float4* dst = (float4*)(Hout + (size_t)t * DD);
  dst[tid] = s[tid];
  dst[tid + 256] = s[tid + 256];
}

template<bool ADDIN, bool WF32, bool FINAL>
__launch_bounds__(256)
__global__ void k_addrms(const float* __restrict__ Hin, float* __restrict__ Res,
                         const float* __restrict__ W,
                         bf16* __restrict__ Xb, float* __restrict__ Xf)
{
  const int t = blockIdx.x, tid = threadIdx.x;
  const size_t base = (size_t)t * DD + tid * 8;
  float x[8];
  {
    const float4* hp = (const float4*)(Hin + base);
    float4 a = hp[0], b = hp[1];
    x[0]=a.x; x[1]=a.y; x[2]=a.z; x[3]=a.w;
    x[4]=b.x; x[5]=b.y; x[6]=b.z; x[7]=b.w;
    if (ADDIN) {
      const float4* rp = (const float4*)(Res + base);
      float4 c = rp[0], d = rp[1];
      x[0]+=c.x; x[1]+=c.y; x[2]+=c.z; x[3]+=c.w;
      x[4]+=d.x; x[5]+=d.y; x[6]+=d.z; x[7]+=d.w;
    }
  }
  {
    float4* rp = (float4*)(Res + base);
    rp[0] = make_float4(x[0], x[1], x[2], x[3]);
    rp[1] = make_float4(x[4], x[5], x[6], x[7]);
  }
  float ss = 0.f;
#pragma unroll
  for (int j = 0; j < 8; ++j) ss += x[j] * x[j];
#pragma unroll
  for (int off = 32; off; off >>= 1) ss += __shfl_xor(ss, off, 64);
  __shared__ float red[4];
  if ((tid & 63) == 0) red[tid >> 6] = ss;
  __syncthreads();
  float tot = red[0] + red[1] + red[2] + red[3];
  float sc = rsqrtf(tot * (1.0f / DD) + 1e-6f);
  float y[8];
#pragma unroll
  for (int j = 0; j < 8; ++j) y[j] = x[j] * sc * W[tid * 8 + j];
  if (!FINAL) {
    union { bf16 b[8]; uint4 u; } pk;
#pragma unroll
    for (int j = 0; j < 8; ++j) pk.b[j] = (bf16)y[j];
    *(uint4*)(Xb + base) = pk.u;
  }
  if (WF32 || FINAL) {
    float4* xp = (float4*)(Xf + base);
    xp[0] = make_float4(y[0], y[1], y[2], y[3]);
    xp[1] = make_float4(y[4], y[5], y[6], y[7]);
  }
}

__global__ void k_rope2(bf16* __restrict__ Qh, bf16* __restrict__ Ql,
                        bf16* __restrict__ Kh, bf16* __restrict__ Kl,
                        const int* __restrict__ pos)
{
  int idx = blockIdx.x * 256 + threadIdx.x;
  int d = idx & 63;
  int h = (idx >> 6) & (HH - 1);
  int t = idx >> 10;
  if (t >= TT) return;
  double inv = pow(1.0e6, -(double)d / 64.0);
  double ang = (double)pos[t] * inv;
  double sd, cd;
  sincos(ang, &sd, &cd);
  float sn = (float)sd, cs = (float)cd;
  size_t base = (size_t)t * DD + h * HDIM + d;
  float q1 = (float)Qh[base] + (float)Ql[base];
  float q2 = (float)Qh[base + 64] + (float)Ql[base + 64];
  float qa = q1 * cs - q2 * sn, qb = q1 * sn + q2 * cs;
  bf16 hb, lb;
  split1(qa, hb, lb); Qh[base] = hb;      Ql[base] = lb;
  split1(qb, hb, lb); Qh[base + 64] = hb; Ql[base + 64] = lb;
  float k1 = (float)Kh[base] + (float)Kl[base];
  float k2 = (float)Kh[base + 64] + (float)Kl[base + 64];
  float ka = k1 * cs - k2 * sn, kb2 = k1 * sn + k2 * cs;
  split1(ka, hb, lb);  Kh[base] = hb;      Kl[base] = lb;
  split1(kb2, hb, lb); Kh[base + 64] = hb; Kl[base + 64] = lb;
}

__launch_bounds__(64)
__global__ void k_router(const float* __restrict__ Xf, const float* __restrict__ RW,
                         const float* __restrict__ SGW, int* __restrict__ eidx,
                         float* __restrict__ ew, float* __restrict__ sgate,
                         int* __restrict__ cnt)
{
  const int t = blockIdx.x, lane = threadIdx.x;
  const float* x = Xf + (size_t)t * DD;
  float acc[8] = {0,0,0,0,0,0,0,0};
  float sg = 0.f;
  for (int i = lane; i < DD; i += 64) {
    float xv = x[i];
    const float4* w = (const float4*)(RW + (size_t)i * NE);
    float4 w0 = w[0], w1 = w[1];
    acc[0] += xv * w0.x; acc[1] += xv * w0.y; acc[2] += xv * w0.z; acc[3] += xv * w0.w;
    acc[4] += xv * w1.x; acc[5] += xv * w1.y; acc[6] += xv * w1.z; acc[7] += xv * w1.w;
    sg += xv * SGW[i];
  }
#pragma unroll
  for (int off = 32; off; off >>= 1) {
#pragma unroll
    for (int e = 0; e < 8; ++e) acc[e] += __shfl_xor(acc[e], off, 64);
    sg += __shfl_xor(sg, off, 64);
  }
  if (lane == 0) {
    int i0 = 0; float v0 = acc[0];
    for (int e = 1; e < 8; ++e) if (acc[e] > v0) { v0 = acc[e]; i0 = e; }
    int i1 = -1; float v1 = -1e30f;
    for (int e = 0; e < 8; ++e) if (e != i0 && acc[e] > v1) { v1 = acc[e]; i1 = e; }
    float w0 = 1.f / (1.f + expf(v1 - v0));
    eidx[2*t] = i0; eidx[2*t+1] = i1;
    ew[2*t] = w0; ew[2*t+1] = 1.f - w0;
    sgate[t] = 1.f / (1.f + expf(-sg));
    atomicAdd(&cnt[i0], 1);
    atomicAdd(&cnt[i1], 1);
  }
}

__global__ void k_scan(const int* __restrict__ cnt, int* __restrict__ ofs)
{
  if (threadIdx.x == 0) {
    int s = 0;
    for (int e = 0; e < NE; ++e) { ofs[e] = s; s += cnt[e]; }
    ofs[NE] = s;
  }
}

__global__ void k_assign(const int* __restrict__ eidx, const int* __restrict__ ofs,
                         int* __restrict__ cursor, int* __restrict__ perm,
                         int* __restrict__ posof)
{
  int t = blockIdx.x * 256 + threadIdx.x;
  if (t >= TT) return;
#pragma unroll
  for (int j = 0; j < 2; ++j) {
    int e = eidx[2*t + j];
    int p = ofs[e] + atomicAdd(&cursor[e], 1);
    perm[p] = t;
    posof[2*t + j] = p;
  }
}

__global__ void k_silumul(bf16* __restrict__ G, const bf16* __restrict__ U, int n)
{
  int i = (blockIdx.x * 256 + threadIdx.x) * 8;
  if (i >= n) return;
  bf16x8 gv = *(const bf16x8*)(G + i);
  bf16x8 uv = *(const bf16x8*)(U + i);
  bf16x8 r;
#pragma unroll
  for (int j = 0; j < 8; ++j) {
    float gg = (float)gv[j];
    float uu = (float)uv[j];
    float s = gg / (1.f + expf(-gg));
    r[j] = (bf16)(s * uu);
  }
  *(bf16x8*)(G + i) = r;
}

__global__ void k_silumul_f(float* __restrict__ G, const float* __restrict__ U, int n)
{
  int i = (blockIdx.x * 256 + threadIdx.x) * 4;
  if (i >= n) return;
  float4 g = *(const float4*)(G + i);
  float4 u = *(const float4*)(U + i);
  float4 r;
  r.x = g.x / (1.f + expf(-g.x)) * u.x;
  r.y = g.y / (1.f + expf(-g.y)) * u.y;
  r.z = g.z / (1.f + expf(-g.z)) * u.z;
  r.w = g.w / (1.f + expf(-g.w)) * u.w;
  *(float4*)(G + i) = r;
}

template<bool YF32>
__global__ void k_combine(const void* __restrict__ Yv, const float* __restrict__ SH,
                          const float* __restrict__ sgate, const float* __restrict__ ew,
                          const int* __restrict__ posof, float* __restrict__ Hout)
{
  int t = blockIdx.x, tid = threadIdx.x;
  int p0 = posof[2*t], p1 = posof[2*t+1];
  float w0 = ew[2*t], w1 = ew[2*t+1];
  float sgv = sgate[t];
  int d0 = tid * 8;
  float y0[8], y1[8];
  if (YF32) {
    const float* Y = (const float*)Yv;
    const float4* a = (const float4*)(Y + (size_t)p0 * DD + d0);
    const float4* b = (const float4*)(Y + (size_t)p1 * DD + d0);
    float4 a0 = a[0], a1 = a[1], b0 = b[0], b1 = b[1];
    y0[0]=a0.x; y0[1]=a0.y; y0[2]=a0.z; y0[3]=a0.w; y0[4]=a1.x; y0[5]=a1.y; y0[6]=a1.z; y0[7]=a1.w;
    y1[0]=b0.x; y1[1]=b0.y; y1[2]=b0.z; y1[3]=b0.w; y1[4]=b1.x; y1[5]=b1.y; y1[6]=b1.z; y1[7]=b1.w;
  } else {
    const bf16* Y = (const bf16*)Yv;
    bf16x8 a = *(const bf16x8*)(Y + (size_t)p0 * DD + d0);
    bf16x8 b = *(const bf16x8*)(Y + (size_t)p1 * DD + d0);
#pragma unroll
    for (int j = 0; j < 8; ++j) { y0[j] = (float)a[j]; y1[j] = (float)b[j]; }
  }
  const float4* shp = (const float4*)(SH + (size_t)t * DD + d0);
  float4 sa = shp[0], sb = shp[1];
  float shv[8] = {sa.x, sa.y, sa.z, sa.w, sb.x, sb.y, sb.z, sb.w};
  float out[8];
#pragma unroll
  for (int j = 0; j < 8; ++j)
    out[j] = (y0[j] * w0 + y1[j] * w1 + sgv * shv[j]) * 0.70710678118654752f;
  float4* op = (float4*)(Hout + (size_t)t * DD + d0);
  op[0] = make_float4(out[0], out[1], out[2], out[3]);
  op[1] = make_float4(out[4], out[5], out[6], out[7]);
}

// -------------------------------------------------------------- driver ------
extern "C" void kernel_launch(void* const* d_in, const int* in_sizes, int n_in,
                              void* d_out, int out_size, void* d_ws, size_t ws_size,
                              hipStream_t stream)
{
  (void)in_sizes; (void)n_in; (void)out_size; (void)ws_size;
  const int*   ids  = (const int*)d_in[0];
  const int*   pos  = (const int*)d_in[1];
  const float* emb  = (const float*)d_in[2];
  const float* qw   = (const float*)d_in[3];
  const float* kw   = (const float*)d_in[4];
  const float* vw   = (const float*)d_in[5];
  const float* ow   = (const float*)d_in[6];
  const float* ln1  = (const float*)d_in[7];
  const float* ln2  = (const float*)d_in[8];
  const float* rw   = (const float*)d_in[9];
  const float* sgw  = (const float*)d_in[10];
  const float* wg   = (const float*)d_in[11];
  const float* wu   = (const float*)d_in[12];
  const float* wd   = (const float*)d_in[13];
  const float* swg  = (const float*)d_in[14];
  const float* swu  = (const float*)d_in[15];
  const float* swd  = (const float*)d_in[16];
  const float* fln  = (const float*)d_in[17];

  char* p = (char*)d_ws;
  auto alloc = [&](size_t b) { char* r = p; p += (b + 255) & ~(size_t)255; return r; };

  const size_t TD = (size_t)TT * DD;
  float* resid = (float*)alloc(TD * 4);
  float* hbuf  = (float*)alloc(TD * 4);
  float* xf    = (float*)alloc(TD * 4);
  bf16*  xb    = (bf16*) alloc(TD * 2);
  bf16*  qhb   = (bf16*) alloc(TD * 2);
  bf16*  qlb   = (bf16*) alloc(TD * 2);
  bf16*  khb   = (bf16*) alloc(TD * 2);
  bf16*  klb   = (bf16*) alloc(TD * 2);
  bf16*  vth   = (bf16*) alloc(TD * 2);
  bf16*  vtl   = (bf16*) alloc(TD * 2);
  float* shb   = (float*)alloc(TD * 4);
  int*   eidx  = (int*)  alloc((size_t)TT * TOPK * 4);
  float* ewb   = (float*)alloc((size_t)TT * TOPK * 4);
  float* sgate = (float*)alloc((size_t)TT * 4);
  int*   perm  = (int*)  alloc((size_t)TT * TOPK * 4);
  int*   posof = (int*)  alloc((size_t)TT * TOPK * 4);
  int*   cnt   = (int*)  alloc(64);
  int*   ofs   = (int*)  alloc(64);
  int*   cursor = cnt + 8;

  const size_t SGF = (size_t)TT * FSS;
  const size_t GEF = (size_t)TT * TOPK * FF;
  char* region = alloc(2 * SGF * 4 + 2 * GEF * 4 + (size_t)TT * TOPK * DD * 4);
  float* aof  = (float*)region;
  float* sgbf = (float*)region;
  float* subf = sgbf + SGF;
  float* gebf = subf + SGF;
  float* uebf = gebf + GEF;
  float* ybf  = uebf + GEF;
  bf16* sgb = (bf16*)region;
  bf16* sub = sgb + SGF;
  bf16* geb = sub + SGF;
  bf16* ueb = geb + GEF;
  bf16* yb  = ueb + GEF;

  k_embed<<<TT, 256, 0, stream>>>(ids, emb, hbuf);

  for (int l = 0; l < NL; ++l) {
    const float* qw_l  = qw  + (size_t)l * DD * DD;
    const float* kw_l  = kw  + (size_t)l * DD * DD;
    const float* vw_l  = vw  + (size_t)l * DD * DD;
    const float* ow_l  = ow  + (size_t)l * DD * DD;
    const float* ln1_l = ln1 + (size_t)l * DD;
    const float* ln2_l = ln2 + (size_t)l * DD;
    const float* rw_l  = rw  + (size_t)l * DD * NE;
    const float* sgw_l = sgw + (size_t)l * DD;
    const float* wg_l  = wg  + (size_t)l * NE * DD * FF;
    const float* wu_l  = wu  + (size_t)l * NE * DD * FF;
    const float* wd_l  = wd  + (size_t)l * NE * FF * DD;
    const float* swg_l = swg + (size_t)l * DD * FSS;
    const float* swu_l = swu + (size_t)l * DD * FSS;
    const float* swd_l = swd + (size_t)l * FSS * DD;

    if (l == 0)
      k_addrms<false,true,false><<<TT,256,0,stream>>>(hbuf, resid, ln1_l, xb, xf);
    else
      k_addrms<true, true,false><<<TT,256,0,stream>>>(hbuf, resid, ln1_l, xb, xf);

    k_gemms<64,64,false,false,3><<<dim3(32,32),256,0,stream>>>(xf, qw_l, qhb, qlb, TT, DD, DD, DD, DD, nullptr,nullptr,nullptr);
    k_gemms<64,64,false,false,3><<<dim3(32,32),256,0,stream>>>(xf, kw_l, khb, klb, TT, DD, DD, DD, DD, nullptr,nullptr,nullptr);
    k_gemms<64,64,false,false,4><<<dim3(32,32),256,0,stream>>>(xf, vw_l, vth, vtl, TT, DD, DD, DD, TT, nullptr,nullptr,nullptr);
    k_rope2<<<(TT*HH*64)/256, 256, 0, stream>>>(qhb, qlb, khb, klb, pos);
    k_attns<<<dim3(TT/64, HH), 256, 0, stream>>>(qhb, qlb, khb, klb, vth, vtl, aof);
    k_gemms<64,64,false,false,1><<<dim3(32,32),256,0,stream>>>(aof, ow_l, hbuf, nullptr, TT, DD, DD, DD, DD, nullptr,nullptr,nullptr);

    k_addrms<true,true,false><<<TT,256,0,stream>>>(hbuf, resid, ln2_l, xb, xf);

    hipMemsetAsync(cnt, 0, 64, stream);
    k_router<<<TT, 64, 0, stream>>>(xf, rw_l, sgw_l, eidx, ewb, sgate, cnt);
    k_scan<<<1, 64, 0, stream>>>(cnt, ofs);
    k_assign<<<TT/256, 256, 0, stream>>>(eidx, ofs, cursor, perm, posof);

    if (l < NL - 1) {
      k_gemms<128,128,false,false,1><<<dim3(16,FSS/128),256,0,stream>>>(xf, swg_l, sgbf, nullptr, TT, FSS, DD, DD, FSS, nullptr,nullptr,nullptr);
      k_gemms<128,128,false,false,1><<<dim3(16,FSS/128),256,0,stream>>>(xf, swu_l, subf, nullptr, TT, FSS, DD, DD, FSS, nullptr,nullptr,nullptr);
      k_silumul_f<<<(TT*FSS/4)/256, 256, 0, stream>>>(sgbf, subf, TT*FSS);
      k_gemms<64,64,false,false,1><<<dim3(32,32),256,0,stream>>>(sgbf, swd_l, shb, nullptr, TT, DD, FSS, FSS, DD, nullptr,nullptr,nullptr);

      k_gemms<128,128,true,true,1><<<dim3(16,FF/128,NE),256,0,stream>>>(xf, wg_l, gebf, nullptr, TT, FF, DD, DD, FF, perm, cnt, ofs);
      k_gemms<128,128,true,true,1><<<dim3(16,FF/128,NE),256,0,stream>>>(xf, wu_l, uebf, nullptr, TT, FF, DD, DD, FF, perm, cnt, ofs);
      k_silumul_f<<<(TT*TOPK*FF/4)/256, 256, 0, stream>>>(gebf, uebf, TT*TOPK*FF);
      k_gemms<64,64,true,false,1><<<dim3(32,32,NE),256,0,stream>>>(gebf, wd_l, ybf, nullptr, TT, DD, FF, FF, DD, nullptr, cnt, ofs);
      k_combine<true><<<TT, 256, 0, stream>>>(ybf, shb, sgate, ewb, posof, hbuf);
    } else {
      k_gemm<false,false,0><<<dim3(16,FSS/BN),256,0,stream>>>(xb, swg_l, sgb, TT, FSS, DD, DD, FSS, nullptr,nullptr,nullptr);
      k_gemm<false,false,0><<<dim3(16,FSS/BN),256,0,stream>>>(xb, swu_l, sub, TT, FSS, DD, DD, FSS, nullptr,nullptr,nullptr);
      k_silumul<<<(TT*FSS/8)/256, 256, 0, stream>>>(sgb, sub, TT*FSS);
      k_gemm<false,false,1><<<dim3(16,16),256,0,stream>>>(sgb, swd_l, shb, TT, DD, FSS, FSS, DD, nullptr,nullptr,nullptr);

      k_gemm<true,true,0><<<dim3(16,FF/BN,NE),256,0,stream>>>(xb, wg_l, geb, TT, FF, DD, DD, FF, perm, cnt, ofs);
      k_gemm<true,true,0><<<dim3(16,FF/BN,NE),256,0,stream>>>(xb, wu_l, ueb, TT, FF, DD, DD, FF, perm, cnt, ofs);
      k_silumul<<<(TT*TOPK*FF/8)/256, 256, 0, stream>>>(geb, ueb, TT*TOPK*FF);
      k_gemm<true,false,0><<<dim3(16,16,NE),256,0,stream>>>(geb, wd_l, yb, TT, DD, FF, FF, DD, nullptr, cnt, ofs);
      k_combine<false><<<TT, 256, 0, stream>>>(yb, shb, sgate, ewb, posof, hbuf);
    }
  }

  k_addrms<true,false,true><<<TT,256,0,stream>>>(hbuf, resid, fln, nullptr, (float*)d_out);
}

// Round 5
// 4335.864 us; speedup vs baseline: 1.6845x; 1.4755x over previous
//
#include <hip/hip_runtime.h>
#include <stdint.h>

#define TT 2048
#define DD 2048
#define HH 16
#define HDIM 128
#define NE 8
#define TOPK 2
#define FF 1408
#define FSS 5632
#define NL 2

typedef __bf16 bf16;
typedef __bf16 bf16x2 __attribute__((ext_vector_type(2)));
typedef __bf16 bf16x4 __attribute__((ext_vector_type(4)));
typedef __bf16 bf16x8 __attribute__((ext_vector_type(8)));
typedef float f32x4 __attribute__((ext_vector_type(4)));

__device__ __forceinline__ void split1(float f, bf16& h, bf16& l) {
  bf16 hb = (bf16)f;
  h = hb;
  l = (bf16)(f - (float)hb);
}

__device__ __forceinline__ void gload16(const void* g, void* l) {
  __builtin_amdgcn_global_load_lds((const __attribute__((address_space(1))) void*)g,
                                   (__attribute__((address_space(3))) void*)l, 16, 0, 0);
}

// ------------------------------------------------ weight transpose+convert --
// W f32 [Kd][N] (N contiguous) -> Wh/Wl bf16 [N][Kd] (Kd contiguous).
// grid (Kd/64, N/64, E); blockIdx.z selects expert slab of Kd*N.
template<bool LO>
__launch_bounds__(256)
__global__ void k_wtrans(const float* __restrict__ W, bf16* __restrict__ Wh,
                         bf16* __restrict__ Wl, int Kd, int N)
{
  __shared__ float T[64][68];
  const size_t slab = (size_t)blockIdx.z * (size_t)Kd * (size_t)N;
  const float* Wp = W + slab;
  const int k0 = blockIdx.x * 64, n0 = blockIdx.y * 64;
  const int tid = threadIdx.x;
  const int rr = tid >> 2, c4 = (tid & 3) * 4;
  const float* src = Wp + (size_t)(k0 + rr) * N + n0 + c4;
#pragma unroll
  for (int j = 0; j < 4; ++j) {
    f32x4 v = *(const f32x4*)(src + j * 16);
    *(f32x4*)&T[rr][c4 + j * 16] = v;
  }
  __syncthreads();
  const int nn = tid >> 2, kk = (tid & 3) * 16;
  bf16x8 h0, h1, l0, l1;
#pragma unroll
  for (int j = 0; j < 8; ++j) {
    bf16 hb, lb;
    split1(T[kk + j][nn], hb, lb);
    h0[j] = hb; l0[j] = lb;
    split1(T[kk + 8 + j][nn], hb, lb);
    h1[j] = hb; l1[j] = lb;
  }
  size_t out = slab + (size_t)(n0 + nn) * Kd + k0 + kk;
  *(bf16x8*)&Wh[out] = h0;
  *(bf16x8*)&Wh[out + 8] = h1;
  if (LO) {
    *(bf16x8*)&Wl[out] = l0;
    *(bf16x8*)&Wl[out + 8] = l1;
  }
}

// ----------------------------------------------------- planar bf16 GEMM -----
// C[M,N] = (Ah+Al)[M,K] @ (Bh+Bl)[N,K]^T, NT=3: hh+hl+lh; NT=1: hh only.
// Tile 64x128, BK=32, global_load_lds staging, m97-style 2-barrier loop.
// OM: 1 = f32 out, 3 = bf16 hi/lo planes out, 4 = planes transposed out.
template<int NT, bool EXPERT, bool GATHER, int OM>
__launch_bounds__(256, 4)
__global__ void k_gemmp(const bf16* __restrict__ Ah, const bf16* __restrict__ Al,
                        const bf16* __restrict__ Bh, const bf16* __restrict__ Bl,
                        void* __restrict__ C1, void* __restrict__ C2,
                        int M, int N, int Kd, int lda, int ldc,
                        const int* __restrict__ perm, const int* __restrict__ cnt,
                        const int* __restrict__ ofs)
{
  constexpr int PL = (NT == 3) ? 2 : 1;
  constexpr int AISS = PL * 4;          // A wave-issues (64 rows * 32k * 2B / 1KB) per plane = 4
  constexpr int BISS = PL * 8;          // B wave-issues per plane = 8
  constexpr int TI = AISS + BISS;
  constexpr int QPW = TI / 4;

  int m_count = M, row_base = 0;
  size_t boff = 0;
  if (EXPERT) {
    int e = blockIdx.z;
    m_count = cnt[e];
    if ((int)(blockIdx.x * 64) >= m_count) return;
    row_base = ofs[e];
    boff = (size_t)e * (size_t)N * (size_t)Kd;
  }
  const int tid = threadIdx.x, lane = tid & 63, wid = tid >> 6;
  const int wm = (wid >> 1) * 32, wn = (wid & 1) * 64;
  const int lr = lane & 15, g = lane >> 4;
  const int n0 = blockIdx.y * 128;
  const int m0 = blockIdx.x * 64;

  __shared__ bf16 As[PL][64][32];
  __shared__ bf16 Bs[PL][128][32];

  // per-thread source pointers for this thread's wave-issues (fixed over K)
  const bf16* srcp[QPW];
#pragma unroll
  for (int j = 0; j < QPW; ++j) {
    int q = wid * QPW + j;
    int r16 = lane >> 2, kc = lane & 3;
    if (q < AISS) {
      int pl = q >> 2, sub = q & 3;
      int r = sub * 16 + r16;
      int tok;
      if (EXPERT) {
        int lrow = m0 + r;
        if (lrow >= m_count) lrow = m_count - 1;
        tok = GATHER ? perm[row_base + lrow] : (row_base + lrow);
      } else {
        tok = m0 + r;
      }
      const bf16* base = (pl == 0) ? Ah : Al;
      srcp[j] = base + (size_t)tok * lda + kc * 8;
    } else {
      int qb = q - AISS;
      int pl = qb >> 3, sub = qb & 7;
      int nrow = sub * 16 + r16;
      const bf16* base = (pl == 0) ? Bh : Bl;
      srcp[j] = base + boff + (size_t)(n0 + nrow) * Kd + kc * 8;
    }
  }

  f32x4 acc[2][4];
#pragma unroll
  for (int i = 0; i < 2; ++i)
#pragma unroll
    for (int j = 0; j < 4; ++j)
      acc[i][j] = (f32x4){0.f, 0.f, 0.f, 0.f};

  auto ISSUE = [&](int k0) {
#pragma unroll
    for (int j = 0; j < QPW; ++j) {
      int q = wid * QPW + j;
      bf16* dst;
      if (q < AISS) {
        int pl = q >> 2, sub = q & 3;
        dst = &As[pl][sub * 16][0];
      } else {
        int qb = q - AISS;
        int pl = qb >> 3, sub = qb & 7;
        dst = &Bs[pl][sub * 16][0];
      }
      gload16(srcp[j] + k0, dst);
    }
  };

  const int NTk = Kd >> 5;
  ISSUE(0);
  for (int t = 0; t < NTk; ++t) {
    __syncthreads();                       // drains vmcnt: tile t resident
    bf16x8 bfr[4][PL], afr[2][PL];
#pragma unroll
    for (int jj = 0; jj < 4; ++jj)
#pragma unroll
      for (int pl = 0; pl < PL; ++pl)
        bfr[jj][pl] = *(const bf16x8*)&Bs[pl][wn + jj * 16 + lr][g * 8];
#pragma unroll
    for (int i = 0; i < 2; ++i)
#pragma unroll
      for (int pl = 0; pl < PL; ++pl)
        afr[i][pl] = *(const bf16x8*)&As[pl][wm + i * 16 + lr][g * 8];
    __syncthreads();                       // all waves done reading LDS
    if (t + 1 < NTk) ISSUE((t + 1) << 5);  // overlap next-tile loads with MFMA
#pragma unroll
    for (int i = 0; i < 2; ++i)
#pragma unroll
      for (int jj = 0; jj < 4; ++jj) {
        f32x4 a2 = acc[i][jj];
        a2 = __builtin_amdgcn_mfma_f32_16x16x32_bf16(afr[i][0], bfr[jj][0], a2, 0, 0, 0);
        if (NT == 3) {
          a2 = __builtin_amdgcn_mfma_f32_16x16x32_bf16(afr[i][0], bfr[jj][1], a2, 0, 0, 0);
          a2 = __builtin_amdgcn_mfma_f32_16x16x32_bf16(afr[i][1], bfr[jj][0], a2, 0, 0, 0);
        }
        acc[i][jj] = a2;
      }
  }

  const int r0 = g * 4;
#pragma unroll
  for (int i = 0; i < 2; ++i) {
    int lrow0 = m0 + wm + i * 16 + r0;
#pragma unroll
    for (int j = 0; j < 4; ++j) {
      int col = n0 + wn + j * 16 + lr;
      if (OM == 4) {
        bf16x4 ph, pl;
#pragma unroll
        for (int r = 0; r < 4; ++r) { bf16 hb, lb; split1(acc[i][j][r], hb, lb); ph[r] = hb; pl[r] = lb; }
        *(bf16x4*)&((bf16*)C1)[(size_t)col * ldc + lrow0] = ph;
        *(bf16x4*)&((bf16*)C2)[(size_t)col * ldc + lrow0] = pl;
      } else {
#pragma unroll
        for (int r = 0; r < 4; ++r) {
          int lrow = lrow0 + r;
          if (EXPERT && lrow >= m_count) continue;
          size_t off = (size_t)(row_base + lrow) * ldc + col;
          if (OM == 1) {
            ((float*)C1)[off] = acc[i][j][r];
          } else {  // OM == 3
            bf16 hb, lb; split1(acc[i][j][r], hb, lb);
            ((bf16*)C1)[off] = hb;
            ((bf16*)C2)[off] = lb;
          }
        }
      }
    }
  }
}

// ------------------------------------ split-precision flash attention -------
__launch_bounds__(256)
__global__ void k_attns(const bf16* __restrict__ Qh, const bf16* __restrict__ Ql,
                        const bf16* __restrict__ Kh, const bf16* __restrict__ Kl,
                        const bf16* __restrict__ Vh, const bf16* __restrict__ Vl,
                        bf16* __restrict__ Oh, bf16* __restrict__ Ol)
{
  const int lane = threadIdx.x & 63, wid = threadIdx.x >> 6;
  const int head = blockIdx.y;
  const int qbase = blockIdx.x * 64 + wid * 16;
  const int lr = lane & 15, g = lane >> 4;
  __shared__ bf16 pl_h[4][16][40];
  __shared__ bf16 pl_l[4][16][40];

  bf16x8 qfh[4], qfl[4];
  {
    size_t qoff = (size_t)(qbase + lr) * DD + head * HDIM;
#pragma unroll
    for (int c = 0; c < 4; ++c) {
      qfh[c] = *(const bf16x8*)(Qh + qoff + c * 32 + g * 8);
      qfl[c] = *(const bf16x8*)(Ql + qoff + c * 32 + g * 8);
    }
  }

  f32x4 o[8];
#pragma unroll
  for (int d = 0; d < 8; ++d) o[d] = (f32x4){0.f, 0.f, 0.f, 0.f};
  float m_r[4] = {-1e30f, -1e30f, -1e30f, -1e30f};
  float l_r[4] = {0.f, 0.f, 0.f, 0.f};

  for (int kb = 0; kb < qbase + 16; kb += 32) {
    f32x4 s0 = {0.f,0.f,0.f,0.f}, s1 = {0.f,0.f,0.f,0.f};
    size_t k0off = (size_t)(kb + lr) * DD + head * HDIM;
    size_t k1off = k0off + (size_t)16 * DD;
#pragma unroll
    for (int c = 0; c < 4; ++c) {
      bf16x8 kh = *(const bf16x8*)(Kh + k0off + c * 32 + g * 8);
      bf16x8 kl = *(const bf16x8*)(Kl + k0off + c * 32 + g * 8);
      s0 = __builtin_amdgcn_mfma_f32_16x16x32_bf16(qfh[c], kh, s0, 0, 0, 0);
      s0 = __builtin_amdgcn_mfma_f32_16x16x32_bf16(qfh[c], kl, s0, 0, 0, 0);
      s0 = __builtin_amdgcn_mfma_f32_16x16x32_bf16(qfl[c], kh, s0, 0, 0, 0);
    }
#pragma unroll
    for (int c = 0; c < 4; ++c) {
      bf16x8 kh = *(const bf16x8*)(Kh + k1off + c * 32 + g * 8);
      bf16x8 kl = *(const bf16x8*)(Kl + k1off + c * 32 + g * 8);
      s1 = __builtin_amdgcn_mfma_f32_16x16x32_bf16(qfh[c], kh, s1, 0, 0, 0);
      s1 = __builtin_amdgcn_mfma_f32_16x16x32_bf16(qfh[c], kl, s1, 0, 0, 0);
      s1 = __builtin_amdgcn_mfma_f32_16x16x32_bf16(qfl[c], kh, s1, 0, 0, 0);
    }
    float p0[4], p1[4], mx[4], alpha[4];
#pragma unroll
    for (int r = 0; r < 4; ++r) {
      int q = qbase + g * 4 + r;
      float a0 = s0[r] * 0.08838834764831845f;
      float a1 = s1[r] * 0.08838834764831845f;
      if (kb + lr > q)      a0 = -1e30f;
      if (kb + 16 + lr > q) a1 = -1e30f;
      p0[r] = a0; p1[r] = a1;
      mx[r] = fmaxf(a0, a1);
    }
#pragma unroll
    for (int off = 1; off < 16; off <<= 1)
#pragma unroll
      for (int r = 0; r < 4; ++r) mx[r] = fmaxf(mx[r], __shfl_xor(mx[r], off, 64));
#pragma unroll
    for (int r = 0; r < 4; ++r) {
      float mn = fmaxf(m_r[r], mx[r]);
      alpha[r] = __expf(m_r[r] - mn);
      m_r[r] = mn;
      p0[r] = __expf(p0[r] - mn);
      p1[r] = __expf(p1[r] - mn);
    }
    float ps[4];
#pragma unroll
    for (int r = 0; r < 4; ++r) ps[r] = p0[r] + p1[r];
#pragma unroll
    for (int off = 1; off < 16; off <<= 1)
#pragma unroll
      for (int r = 0; r < 4; ++r) ps[r] += __shfl_xor(ps[r], off, 64);
#pragma unroll
    for (int r = 0; r < 4; ++r) l_r[r] = l_r[r] * alpha[r] + ps[r];
#pragma unroll
    for (int d = 0; d < 8; ++d)
#pragma unroll
      for (int r = 0; r < 4; ++r) o[d][r] *= alpha[r];
#pragma unroll
    for (int r = 0; r < 4; ++r) {
      bf16 hb, lb;
      split1(p0[r], hb, lb);
      pl_h[wid][g * 4 + r][lr] = hb;
      pl_l[wid][g * 4 + r][lr] = lb;
      split1(p1[r], hb, lb);
      pl_h[wid][g * 4 + r][16 + lr] = hb;
      pl_l[wid][g * 4 + r][16 + lr] = lb;
    }
    bf16x8 pah = *(const bf16x8*)&pl_h[wid][lr][g * 8];
    bf16x8 pal = *(const bf16x8*)&pl_l[wid][lr][g * 8];
#pragma unroll
    for (int d = 0; d < 8; ++d) {
      size_t voff = (size_t)(head * HDIM + d * 16 + lr) * TT + kb + g * 8;
      bf16x8 vfh = *(const bf16x8*)(Vh + voff);
      bf16x8 vfl = *(const bf16x8*)(Vl + voff);
      o[d] = __builtin_amdgcn_mfma_f32_16x16x32_bf16(pah, vfh, o[d], 0, 0, 0);
      o[d] = __builtin_amdgcn_mfma_f32_16x16x32_bf16(pah, vfl, o[d], 0, 0, 0);
      o[d] = __builtin_amdgcn_mfma_f32_16x16x32_bf16(pal, vfh, o[d], 0, 0, 0);
    }
  }
#pragma unroll
  for (int r = 0; r < 4; ++r) l_r[r] = 1.f / l_r[r];
#pragma unroll
  for (int d = 0; d < 8; ++d)
#pragma unroll
    for (int r = 0; r < 4; ++r) {
      bf16 hb, lb;
      split1(o[d][r] * l_r[r], hb, lb);
      size_t oi = (size_t)(qbase + g * 4 + r) * DD + head * HDIM + d * 16 + lr;
      Oh[oi] = hb;
      Ol[oi] = lb;
    }
}

// ------------------------------------------------------------- helpers ------
__global__ void k_embed(const int* __restrict__ ids, const float* __restrict__ Em,
                        float* __restrict__ Hout)
{
  int t = blockIdx.x, tid = threadIdx.x;
  const float4* s = (const float4*)(Em + (size_t)ids[t] * DD);
  float4* dst = (float4*)(Hout + (size_t)t * DD);
  dst[tid] = s[tid];
  dst[tid + 256] = s[tid + 256];
}

template<bool ADDIN, bool WF32, bool FINAL>
__launch_bounds__(256)
__global__ void k_addrms(const float* __restrict__ Hin, float* __restrict__ Res,
                         const float* __restrict__ W,
                         bf16* __restrict__ Xh, bf16* __restrict__ Xl,
                         float* __restrict__ Xf)
{
  const int t = blockIdx.x, tid = threadIdx.x;
  const size_t base = (size_t)t * DD + tid * 8;
  float x[8];
  {
    const float4* hp = (const float4*)(Hin + base);
    float4 a = hp[0], b = hp[1];
    x[0]=a.x; x[1]=a.y; x[2]=a.z; x[3]=a.w;
    x[4]=b.x; x[5]=b.y; x[6]=b.z; x[7]=b.w;
    if (ADDIN) {
      const float4* rp = (const float4*)(Res + base);
      float4 c = rp[0], d = rp[1];
      x[0]+=c.x; x[1]+=c.y; x[2]+=c.z; x[3]+=c.w;
      x[4]+=d.x; x[5]+=d.y; x[6]+=d.z; x[7]+=d.w;
    }
  }
  {
    float4* rp = (float4*)(Res + base);
    rp[0] = make_float4(x[0], x[1], x[2], x[3]);
    rp[1] = make_float4(x[4], x[5], x[6], x[7]);
  }
  float ss = 0.f;
#pragma unroll
  for (int j = 0; j < 8; ++j) ss += x[j] * x[j];
#pragma unroll
  for (int off = 32; off; off >>= 1) ss += __shfl_xor(ss, off, 64);
  __shared__ float red[4];
  if ((tid & 63) == 0) red[tid >> 6] = ss;
  __syncthreads();
  float tot = red[0] + red[1] + red[2] + red[3];
  float sc = rsqrtf(tot * (1.0f / DD) + 1e-6f);
  float y[8];
#pragma unroll
  for (int j = 0; j < 8; ++j) y[j] = x[j] * sc * W[tid * 8 + j];
  if (!FINAL) {
    union { bf16 b[8]; uint4 u; } ph, pl;
#pragma unroll
    for (int j = 0; j < 8; ++j) { bf16 hb, lb; split1(y[j], hb, lb); ph.b[j] = hb; pl.b[j] = lb; }
    *(uint4*)(Xh + base) = ph.u;
    *(uint4*)(Xl + base) = pl.u;
  }
  if (WF32 || FINAL) {
    float4* xp = (float4*)(Xf + base);
    xp[0] = make_float4(y[0], y[1], y[2], y[3]);
    xp[1] = make_float4(y[4], y[5], y[6], y[7]);
  }
}

__global__ void k_rope2(bf16* __restrict__ Qh, bf16* __restrict__ Ql,
                        bf16* __restrict__ Kh, bf16* __restrict__ Kl,
                        const int* __restrict__ pos)
{
  int idx = blockIdx.x * 256 + threadIdx.x;
  int d = idx & 63;
  int h = (idx >> 6) & (HH - 1);
  int t = idx >> 10;
  if (t >= TT) return;
  double inv = pow(1.0e6, -(double)d / 64.0);
  double ang = (double)pos[t] * inv;
  double sd, cd;
  sincos(ang, &sd, &cd);
  float sn = (float)sd, cs = (float)cd;
  size_t base = (size_t)t * DD + h * HDIM + d;
  float q1 = (float)Qh[base] + (float)Ql[base];
  float q2 = (float)Qh[base + 64] + (float)Ql[base + 64];
  float qa = q1 * cs - q2 * sn, qb = q1 * sn + q2 * cs;
  bf16 hb, lb;
  split1(qa, hb, lb); Qh[base] = hb;      Ql[base] = lb;
  split1(qb, hb, lb); Qh[base + 64] = hb; Ql[base + 64] = lb;
  float k1 = (float)Kh[base] + (float)Kl[base];
  float k2 = (float)Kh[base + 64] + (float)Kl[base + 64];
  float ka = k1 * cs - k2 * sn, kb2 = k1 * sn + k2 * cs;
  split1(ka, hb, lb);  Kh[base] = hb;      Kl[base] = lb;
  split1(kb2, hb, lb); Kh[base + 64] = hb; Kl[base + 64] = lb;
}

__launch_bounds__(64)
__global__ void k_router(const float* __restrict__ Xf, const float* __restrict__ RW,
                         const float* __restrict__ SGW, int* __restrict__ eidx,
                         float* __restrict__ ew, float* __restrict__ sgate,
                         int* __restrict__ cnt)
{
  const int t = blockIdx.x, lane = threadIdx.x;
  const float* x = Xf + (size_t)t * DD;
  float acc[8] = {0,0,0,0,0,0,0,0};
  float sg = 0.f;
  for (int i = lane; i < DD; i += 64) {
    float xv = x[i];
    const float4* w = (const float4*)(RW + (size_t)i * NE);
    float4 w0 = w[0], w1 = w[1];
    acc[0] += xv * w0.x; acc[1] += xv * w0.y; acc[2] += xv * w0.z; acc[3] += xv * w0.w;
    acc[4] += xv * w1.x; acc[5] += xv * w1.y; acc[6] += xv * w1.z; acc[7] += xv * w1.w;
    sg += xv * SGW[i];
  }
#pragma unroll
  for (int off = 32; off; off >>= 1) {
#pragma unroll
    for (int e = 0; e < 8; ++e) acc[e] += __shfl_xor(acc[e], off, 64);
    sg += __shfl_xor(sg, off, 64);
  }
  if (lane == 0) {
    int i0 = 0; float v0 = acc[0];
    for (int e = 1; e < 8; ++e) if (acc[e] > v0) { v0 = acc[e]; i0 = e; }
    int i1 = -1; float v1 = -1e30f;
    for (int e = 0; e < 8; ++e) if (e != i0 && acc[e] > v1) { v1 = acc[e]; i1 = e; }
    float w0 = 1.f / (1.f + expf(v1 - v0));
    eidx[2*t] = i0; eidx[2*t+1] = i1;
    ew[2*t] = w0; ew[2*t+1] = 1.f - w0;
    sgate[t] = 1.f / (1.f + expf(-sg));
    atomicAdd(&cnt[i0], 1);
    atomicAdd(&cnt[i1], 1);
  }
}

__global__ void k_scan(const int* __restrict__ cnt, int* __restrict__ ofs)
{
  if (threadIdx.x == 0) {
    int s = 0;
    for (int e = 0; e < NE; ++e) { ofs[e] = s; s += cnt[e]; }
    ofs[NE] = s;
  }
}

__global__ void k_assign(const int* __restrict__ eidx, const int* __restrict__ ofs,
                         int* __restrict__ cursor, int* __restrict__ perm,
                         int* __restrict__ posof)
{
  int t = blockIdx.x * 256 + threadIdx.x;
  if (t >= TT) return;
#pragma unroll
  for (int j = 0; j < 2; ++j) {
    int e = eidx[2*t + j];
    int p = ofs[e] + atomicAdd(&cursor[e], 1);
    perm[p] = t;
    posof[2*t + j] = p;
  }
}

// silu(g)*u from f32 inputs -> bf16 hi/lo planes
__global__ void k_silup(const float* __restrict__ G, const float* __restrict__ U,
                        bf16* __restrict__ H, bf16* __restrict__ L)
{
  int i = (blockIdx.x * 256 + threadIdx.x) * 4;
  float4 g = *(const float4*)(G + i);
  float4 u = *(const float4*)(U + i);
  float s[4];
  s[0] = g.x / (1.f + expf(-g.x)) * u.x;
  s[1] = g.y / (1.f + expf(-g.y)) * u.y;
  s[2] = g.z / (1.f + expf(-g.z)) * u.z;
  s[3] = g.w / (1.f + expf(-g.w)) * u.w;
  bf16x4 h, l;
#pragma unroll
  for (int j = 0; j < 4; ++j) { bf16 hb, lb; split1(s[j], hb, lb); h[j] = hb; l[j] = lb; }
  *(bf16x4*)(H + i) = h;
  *(bf16x4*)(L + i) = l;
}

__global__ void k_combine(const float* __restrict__ Y, const float* __restrict__ SH,
                          const float* __restrict__ sgate, const float* __restrict__ ew,
                          const int* __restrict__ posof, float* __restrict__ Hout)
{
  int t = blockIdx.x, tid = threadIdx.x;
  int p0 = posof[2*t], p1 = posof[2*t+1];
  float w0 = ew[2*t], w1 = ew[2*t+1];
  float sgv = sgate[t];
  int d0 = tid * 8;
  const float4* a = (const float4*)(Y + (size_t)p0 * DD + d0);
  const float4* b = (const float4*)(Y + (size_t)p1 * DD + d0);
  float4 a0 = a[0], a1 = a[1], b0 = b[0], b1 = b[1];
  float y0[8] = {a0.x,a0.y,a0.z,a0.w,a1.x,a1.y,a1.z,a1.w};
  float y1[8] = {b0.x,b0.y,b0.z,b0.w,b1.x,b1.y,b1.z,b1.w};
  const float4* shp = (const float4*)(SH + (size_t)t * DD + d0);
  float4 sa = shp[0], sb = shp[1];
  float shv[8] = {sa.x, sa.y, sa.z, sa.w, sb.x, sb.y, sb.z, sb.w};
  float out[8];
#pragma unroll
  for (int j = 0; j < 8; ++j)
    out[j] = (y0[j] * w0 + y1[j] * w1 + sgv * shv[j]) * 0.70710678118654752f;
  float4* op = (float4*)(Hout + (size_t)t * DD + d0);
  op[0] = make_float4(out[0], out[1], out[2], out[3]);
  op[1] = make_float4(out[4], out[5], out[6], out[7]);
}

// -------------------------------------------------------------- driver ------
extern "C" void kernel_launch(void* const* d_in, const int* in_sizes, int n_in,
                              void* d_out, int out_size, void* d_ws, size_t ws_size,
                              hipStream_t stream)
{
  (void)in_sizes; (void)n_in; (void)out_size; (void)ws_size;
  const int*   ids  = (const int*)d_in[0];
  const int*   pos  = (const int*)d_in[1];
  const float* emb  = (const float*)d_in[2];
  const float* qw   = (const float*)d_in[3];
  const float* kw   = (const float*)d_in[4];
  const float* vw   = (const float*)d_in[5];
  const float* ow   = (const float*)d_in[6];
  const float* ln1  = (const float*)d_in[7];
  const float* ln2  = (const float*)d_in[8];
  const float* rw   = (const float*)d_in[9];
  const float* sgw  = (const float*)d_in[10];
  const float* wg   = (const float*)d_in[11];
  const float* wu   = (const float*)d_in[12];
  const float* wd   = (const float*)d_in[13];
  const float* swg  = (const float*)d_in[14];
  const float* swu  = (const float*)d_in[15];
  const float* swd  = (const float*)d_in[16];
  const float* fln  = (const float*)d_in[17];

  char* p = (char*)d_ws;
  auto alloc = [&](size_t b) { char* r = p; p += (b + 255) & ~(size_t)255; return r; };

  const size_t TD = (size_t)TT * DD;
  float* resid = (float*)alloc(TD * 4);
  float* hbuf  = (float*)alloc(TD * 4);
  float* xf    = (float*)alloc(TD * 4);
  bf16*  xh    = (bf16*) alloc(TD * 2);
  bf16*  xl    = (bf16*) alloc(TD * 2);
  bf16*  qhb   = (bf16*) alloc(TD * 2);
  bf16*  qlb   = (bf16*) alloc(TD * 2);
  bf16*  khb   = (bf16*) alloc(TD * 2);
  bf16*  klb   = (bf16*) alloc(TD * 2);
  bf16*  vth   = (bf16*) alloc(TD * 2);
  bf16*  vtl   = (bf16*) alloc(TD * 2);
  bf16*  aoh   = (bf16*) alloc(TD * 2);
  bf16*  aol   = (bf16*) alloc(TD * 2);
  float* shb   = (float*)alloc(TD * 4);
  const size_t SGF = (size_t)TT * FSS;
  const size_t GEF = (size_t)TT * TOPK * FF;
  bf16*  shph  = (bf16*) alloc(SGF * 2);
  bf16*  shpl  = (bf16*) alloc(SGF * 2);
  bf16*  geph  = (bf16*) alloc(GEF * 2);
  bf16*  gepl  = (bf16*) alloc(GEF * 2);
  // overlaid f32 region: {sgbf, subf} then {gebf, uebf, ybf}
  float* region = (float*)alloc(2 * SGF * 4);
  float* sgbf = region;
  float* subf = region + SGF;
  float* gebf = region;
  float* uebf = region + GEF;
  float* ybf  = region + 2 * GEF;
  // weight plane scratch (reused per matrix): max = wg experts pair
  const size_t WME = (size_t)NE * DD * FF;     // 23.1M elems per plane
  bf16* wbh = (bf16*)alloc(WME * 2);
  bf16* wbl = (bf16*)alloc(WME * 2);
  int*   eidx  = (int*)  alloc((size_t)TT * TOPK * 4);
  float* ewb   = (float*)alloc((size_t)TT * TOPK * 4);
  float* sgate = (float*)alloc((size_t)TT * 4);
  int*   perm  = (int*)  alloc((size_t)TT * TOPK * 4);
  int*   posof = (int*)  alloc((size_t)TT * TOPK * 4);
  int*   cnt   = (int*)  alloc(64);
  int*   ofs   = (int*)  alloc(64);
  int*   cursor = cnt + 8;

  k_embed<<<TT, 256, 0, stream>>>(ids, emb, hbuf);

  for (int l = 0; l < NL; ++l) {
    const float* qw_l  = qw  + (size_t)l * DD * DD;
    const float* kw_l  = kw  + (size_t)l * DD * DD;
    const float* vw_l  = vw  + (size_t)l * DD * DD;
    const float* ow_l  = ow  + (size_t)l * DD * DD;
    const float* ln1_l = ln1 + (size_t)l * DD;
    const float* ln2_l = ln2 + (size_t)l * DD;
    const float* rw_l  = rw  + (size_t)l * DD * NE;
    const float* sgw_l = sgw + (size_t)l * DD;
    const float* wg_l  = wg  + (size_t)l * NE * DD * FF;
    const float* wu_l  = wu  + (size_t)l * NE * DD * FF;
    const float* wd_l  = wd  + (size_t)l * NE * FF * DD;
    const float* swg_l = swg + (size_t)l * DD * FSS;
    const float* swu_l = swu + (size_t)l * DD * FSS;
    const float* swd_l = swd + (size_t)l * FSS * DD;
    const bool last = (l == NL - 1);

    if (l == 0)
      k_addrms<false,false,false><<<TT,256,0,stream>>>(hbuf, resid, ln1_l, xh, xl, nullptr);
    else
      k_addrms<true, false,false><<<TT,256,0,stream>>>(hbuf, resid, ln1_l, xh, xl, nullptr);

    // ---- attention (split everywhere: feeds this layer's ln2 -> router) ----
    k_wtrans<true><<<dim3(32,32),256,0,stream>>>(qw_l, wbh, wbl, DD, DD);
    k_gemmp<3,false,false,3><<<dim3(32,16),256,0,stream>>>(xh, xl, wbh, wbl, qhb, qlb, TT, DD, DD, DD, DD, nullptr,nullptr,nullptr);
    k_wtrans<true><<<dim3(32,32),256,0,stream>>>(kw_l, wbh, wbl, DD, DD);
    k_gemmp<3,false,false,3><<<dim3(32,16),256,0,stream>>>(xh, xl, wbh, wbl, khb, klb, TT, DD, DD, DD, DD, nullptr,nullptr,nullptr);
    k_wtrans<true><<<dim3(32,32),256,0,stream>>>(vw_l, wbh, wbl, DD, DD);
    k_gemmp<3,false,false,4><<<dim3(32,16),256,0,stream>>>(xh, xl, wbh, wbl, vth, vtl, TT, DD, DD, DD, TT, nullptr,nullptr,nullptr);
    k_rope2<<<(TT*HH*64)/256, 256, 0, stream>>>(qhb, qlb, khb, klb, pos);
    k_attns<<<dim3(TT/64, HH), 256, 0, stream>>>(qhb, qlb, khb, klb, vth, vtl, aoh, aol);
    k_wtrans<true><<<dim3(32,32),256,0,stream>>>(ow_l, wbh, wbl, DD, DD);
    k_gemmp<3,false,false,1><<<dim3(32,16),256,0,stream>>>(aoh, aol, wbh, wbl, hbuf, nullptr, TT, DD, DD, DD, DD, nullptr,nullptr,nullptr);

    k_addrms<true,true,false><<<TT,256,0,stream>>>(hbuf, resid, ln2_l, xh, xl, xf);

    hipMemsetAsync(cnt, 0, 64, stream);
    k_router<<<TT, 64, 0, stream>>>(xf, rw_l, sgw_l, eidx, ewb, sgate, cnt);
    k_scan<<<1, 64, 0, stream>>>(cnt, ofs);
    k_assign<<<TT/256, 256, 0, stream>>>(eidx, ofs, cursor, perm, posof);

    // ---- shared expert ----
    if (!last) {
      k_wtrans<true><<<dim3(32,88),256,0,stream>>>(swg_l, wbh, wbl, DD, FSS);
      k_gemmp<3,false,false,1><<<dim3(32,44),256,0,stream>>>(xh, xl, wbh, wbl, sgbf, nullptr, TT, FSS, DD, DD, FSS, nullptr,nullptr,nullptr);
      k_wtrans<true><<<dim3(32,88),256,0,stream>>>(swu_l, wbh, wbl, DD, FSS);
      k_gemmp<3,false,false,1><<<dim3(32,44),256,0,stream>>>(xh, xl, wbh, wbl, subf, nullptr, TT, FSS, DD, DD, FSS, nullptr,nullptr,nullptr);
      k_silup<<<(TT*FSS/4)/256, 256, 0, stream>>>(sgbf, subf, shph, shpl);
      k_wtrans<true><<<dim3(88,32),256,0,stream>>>(swd_l, wbh, wbl, FSS, DD);
      k_gemmp<3,false,false,1><<<dim3(32,16),256,0,stream>>>(shph, shpl, wbh, wbl, shb, nullptr, TT, DD, FSS, FSS, DD, nullptr,nullptr,nullptr);
    } else {
      k_wtrans<false><<<dim3(32,88),256,0,stream>>>(swg_l, wbh, wbl, DD, FSS);
      k_gemmp<1,false,false,1><<<dim3(32,44),256,0,stream>>>(xh, xl, wbh, wbl, sgbf, nullptr, TT, FSS, DD, DD, FSS, nullptr,nullptr,nullptr);
      k_wtrans<false><<<dim3(32,88),256,0,stream>>>(swu_l, wbh, wbl, DD, FSS);
      k_gemmp<1,false,false,1><<<dim3(32,44),256,0,stream>>>(xh, xl, wbh, wbl, subf, nullptr, TT, FSS, DD, DD, FSS, nullptr,nullptr,nullptr);
      k_silup<<<(TT*FSS/4)/256, 256, 0, stream>>>(sgbf, subf, shph, shpl);
      k_wtrans<false><<<dim3(88,32),256,0,stream>>>(swd_l, wbh, wbl, FSS, DD);
      k_gemmp<1,false,false,1><<<dim3(32,16),256,0,stream>>>(shph, shpl, wbh, wbl, shb, nullptr, TT, DD, FSS, FSS, DD, nullptr,nullptr,nullptr);
    }

    // ---- routed experts ----
    if (!last) {
      k_wtrans<true><<<dim3(32,22,NE),256,0,stream>>>(wg_l, wbh, wbl, DD, FF);
      k_gemmp<3,true,true,1><<<dim3(64,11,NE),256,0,stream>>>(xh, xl, wbh, wbl, gebf, nullptr, TT, FF, DD, DD, FF, perm, cnt, ofs);
      k_wtrans<true><<<dim3(32,22,NE),256,0,stream>>>(wu_l, wbh, wbl, DD, FF);
      k_gemmp<3,true,true,1><<<dim3(64,11,NE),256,0,stream>>>(xh, xl, wbh, wbl, uebf, nullptr, TT, FF, DD, DD, FF, perm, cnt, ofs);
      k_silup<<<(GEF/4)/256, 256, 0, stream>>>(gebf, uebf, geph, gepl);
      k_wtrans<true><<<dim3(22,32,NE),256,0,stream>>>(wd_l, wbh, wbl, FF, DD);
      k_gemmp<3,true,false,1><<<dim3(64,16,NE),256,0,stream>>>(geph, gepl, wbh, wbl, ybf, nullptr, TT, DD, FF, FF, DD, nullptr, cnt, ofs);
    } else {
      k_wtrans<false><<<dim3(32,22,NE),256,0,stream>>>(wg_l, wbh, wbl, DD, FF);
      k_gemmp<1,true,true,1><<<dim3(64,11,NE),256,0,stream>>>(xh, xl, wbh, wbl, gebf, nullptr, TT, FF, DD, DD, FF, perm, cnt, ofs);
      k_wtrans<false><<<dim3(32,22,NE),256,0,stream>>>(wu_l, wbh, wbl, DD, FF);
      k_gemmp<1,true,true,1><<<dim3(64,11,NE),256,0,stream>>>(xh, xl, wbh, wbl, uebf, nullptr, TT, FF, DD, DD, FF, perm, cnt, ofs);
      k_silup<<<(GEF/4)/256, 256, 0, stream>>>(gebf, uebf, geph, gepl);
      k_wtrans<false><<<dim3(22,32,NE),256,0,stream>>>(wd_l, wbh, wbl, FF, DD);
      k_gemmp<1,true,false,1><<<dim3(64,16,NE),256,0,stream>>>(geph, gepl, wbh, wbl, ybf, nullptr, TT, DD, FF, FF, DD, nullptr, cnt, ofs);
    }
    k_combine<<<TT, 256, 0, stream>>>(ybf, shb, sgate, ewb, posof, hbuf);
  }

  k_addrms<true,false,true><<<TT,256,0,stream>>>(hbuf, resid, fln, nullptr, nullptr, (float*)d_out);
}

// Round 6
// 3947.449 us; speedup vs baseline: 1.8503x; 1.0984x over previous
//
#include <hip/hip_runtime.h>
#include <stdint.h>

#define TT 2048
#define DD 2048
#define HH 16
#define HDIM 128
#define NE 8
#define TOPK 2
#define FF 1408
#define FSS 5632
#define NL 2

typedef __bf16 bf16;
typedef __bf16 bf16x2 __attribute__((ext_vector_type(2)));
typedef __bf16 bf16x4 __attribute__((ext_vector_type(4)));
typedef __bf16 bf16x8 __attribute__((ext_vector_type(8)));
typedef float f32x4 __attribute__((ext_vector_type(4)));

__device__ __forceinline__ void split1(float f, bf16& h, bf16& l) {
  bf16 hb = (bf16)f;
  h = hb;
  l = (bf16)(f - (float)hb);
}

__device__ __forceinline__ void gload16(const void* g, void* l) {
  __builtin_amdgcn_global_load_lds((const __attribute__((address_space(1))) void*)g,
                                   (__attribute__((address_space(3))) void*)l, 16, 0, 0);
}

// ------------------------------------------------ weight transpose+convert --
// W f32 [Kd][N] (N contiguous) -> Wh/Wl bf16 [N][Kd] (Kd contiguous).
template<bool LO>
__launch_bounds__(256)
__global__ void k_wtrans(const float* __restrict__ W, bf16* __restrict__ Wh,
                         bf16* __restrict__ Wl, int Kd, int N)
{
  __shared__ float T[64][68];
  const size_t slab = (size_t)blockIdx.z * (size_t)Kd * (size_t)N;
  const float* Wp = W + slab;
  const int k0 = blockIdx.x * 64, n0 = blockIdx.y * 64;
  const int tid = threadIdx.x;
  const int rr = tid >> 2, c4 = (tid & 3) * 4;
  const float* src = Wp + (size_t)(k0 + rr) * N + n0 + c4;
#pragma unroll
  for (int j = 0; j < 4; ++j) {
    f32x4 v = *(const f32x4*)(src + j * 16);
    *(f32x4*)&T[rr][c4 + j * 16] = v;
  }
  __syncthreads();
  const int nn = tid >> 2, kk = (tid & 3) * 16;
  bf16x8 h0, h1, l0, l1;
#pragma unroll
  for (int j = 0; j < 8; ++j) {
    bf16 hb, lb;
    split1(T[kk + j][nn], hb, lb);
    h0[j] = hb; l0[j] = lb;
    split1(T[kk + 8 + j][nn], hb, lb);
    h1[j] = hb; l1[j] = lb;
  }
  size_t out = slab + (size_t)(n0 + nn) * Kd + k0 + kk;
  *(bf16x8*)&Wh[out] = h0;
  *(bf16x8*)&Wh[out + 8] = h1;
  if (LO) {
    *(bf16x8*)&Wl[out] = l0;
    *(bf16x8*)&Wl[out + 8] = l1;
  }
}

// ----------------------------------------------------- planar bf16 GEMM -----
// C[M,N] = (Ah+Al)[M,K] @ (Bh+Bl)[N,K]^T, NT=3: hh+hl+lh; NT=1: hh only.
// Tile BMTx128, BK=32, global_load_lds staging, 2-barrier loop.
// OM: 1 = f32 out, 3 = bf16 hi/lo planes out, 4 = planes transposed out.
template<int BMT, int NT, bool EXPERT, bool GATHER, int OM>
__launch_bounds__(256, (BMT == 128 ? 3 : 4))
__global__ void k_gemmp(const bf16* __restrict__ Ah, const bf16* __restrict__ Al,
                        const bf16* __restrict__ Bh, const bf16* __restrict__ Bl,
                        void* __restrict__ C1, void* __restrict__ C2,
                        int M, int N, int Kd, int lda, int ldc,
                        const int* __restrict__ perm, const int* __restrict__ cnt,
                        const int* __restrict__ ofs)
{
  constexpr int PL = (NT == 3) ? 2 : 1;
  constexpr int ASUB = BMT / 16;        // A 16-row subtiles per plane
  constexpr int AISS = PL * ASUB;
  constexpr int BISS = PL * 8;
  constexpr int QPW = (AISS + BISS) / 4;
  constexpr int IF = BMT / 32;

  int m_count = M, row_base = 0;
  size_t boff = 0;
  if (EXPERT) {
    int e = blockIdx.z;
    m_count = cnt[e];
    if ((int)(blockIdx.x * BMT) >= m_count) return;
    row_base = ofs[e];
    boff = (size_t)e * (size_t)N * (size_t)Kd;
  }
  const int tid = threadIdx.x, lane = tid & 63, wid = tid >> 6;
  const int wm = (wid >> 1) * (BMT / 2), wn = (wid & 1) * 64;
  const int lr = lane & 15, g = lane >> 4;
  const int n0 = blockIdx.y * 128;
  const int m0 = blockIdx.x * BMT;

  __shared__ bf16 As[PL][BMT][32];
  __shared__ bf16 Bs[PL][128][32];

  const bf16* srcp[QPW];
#pragma unroll
  for (int j = 0; j < QPW; ++j) {
    int q = wid * QPW + j;
    int r16 = lane >> 2, kc = lane & 3;
    if (q < AISS) {
      int pl = q / ASUB, sub = q % ASUB;
      int r = sub * 16 + r16;
      int tok;
      if (EXPERT) {
        int lrow = m0 + r;
        if (lrow >= m_count) lrow = m_count - 1;
        tok = GATHER ? perm[row_base + lrow] : (row_base + lrow);
      } else {
        tok = m0 + r;
      }
      const bf16* base = (pl == 0) ? Ah : Al;
      srcp[j] = base + (size_t)tok * lda + kc * 8;
    } else {
      int qb = q - AISS;
      int pl = qb >> 3, sub = qb & 7;
      int nrow = sub * 16 + r16;
      const bf16* base = (pl == 0) ? Bh : Bl;
      srcp[j] = base + boff + (size_t)(n0 + nrow) * Kd + kc * 8;
    }
  }

  f32x4 acc[IF][4];
#pragma unroll
  for (int i = 0; i < IF; ++i)
#pragma unroll
    for (int j = 0; j < 4; ++j)
      acc[i][j] = (f32x4){0.f, 0.f, 0.f, 0.f};

  auto ISSUE = [&](int k0) {
#pragma unroll
    for (int j = 0; j < QPW; ++j) {
      int q = wid * QPW + j;
      bf16* dst;
      if (q < AISS) {
        int pl = q / ASUB, sub = q % ASUB;
        dst = &As[pl][sub * 16][0];
      } else {
        int qb = q - AISS;
        int pl = qb >> 3, sub = qb & 7;
        dst = &Bs[pl][sub * 16][0];
      }
      gload16(srcp[j] + k0, dst);
    }
  };

  const int NTk = Kd >> 5;
  ISSUE(0);
  for (int t = 0; t < NTk; ++t) {
    __syncthreads();                       // drains vmcnt: tile t resident
    bf16x8 bfr[4][PL], afr[IF][PL];
#pragma unroll
    for (int jj = 0; jj < 4; ++jj)
#pragma unroll
      for (int pl = 0; pl < PL; ++pl)
        bfr[jj][pl] = *(const bf16x8*)&Bs[pl][wn + jj * 16 + lr][g * 8];
#pragma unroll
    for (int i = 0; i < IF; ++i)
#pragma unroll
      for (int pl = 0; pl < PL; ++pl)
        afr[i][pl] = *(const bf16x8*)&As[pl][wm + i * 16 + lr][g * 8];
    __syncthreads();                       // all waves done reading LDS
    if (t + 1 < NTk) ISSUE((t + 1) << 5);  // overlap next-tile loads with MFMA
#pragma unroll
    for (int i = 0; i < IF; ++i)
#pragma unroll
      for (int jj = 0; jj < 4; ++jj) {
        f32x4 a2 = acc[i][jj];
        a2 = __builtin_amdgcn_mfma_f32_16x16x32_bf16(afr[i][0], bfr[jj][0], a2, 0, 0, 0);
        if (NT == 3) {
          a2 = __builtin_amdgcn_mfma_f32_16x16x32_bf16(afr[i][0], bfr[jj][1], a2, 0, 0, 0);
          a2 = __builtin_amdgcn_mfma_f32_16x16x32_bf16(afr[i][1], bfr[jj][0], a2, 0, 0, 0);
        }
        acc[i][jj] = a2;
      }
  }

  const int r0 = g * 4;
#pragma unroll
  for (int i = 0; i < IF; ++i) {
    int lrow0 = m0 + wm + i * 16 + r0;
#pragma unroll
    for (int j = 0; j < 4; ++j) {
      int col = n0 + wn + j * 16 + lr;
      if (OM == 4) {
        bf16x4 ph, pl;
#pragma unroll
        for (int r = 0; r < 4; ++r) { bf16 hb, lb; split1(acc[i][j][r], hb, lb); ph[r] = hb; pl[r] = lb; }
        *(bf16x4*)&((bf16*)C1)[(size_t)col * ldc + lrow0] = ph;
        *(bf16x4*)&((bf16*)C2)[(size_t)col * ldc + lrow0] = pl;
      } else {
#pragma unroll
        for (int r = 0; r < 4; ++r) {
          int lrow = lrow0 + r;
          if (EXPERT && lrow >= m_count) continue;
          size_t off = (size_t)(row_base + lrow) * ldc + col;
          if (OM == 1) {
            ((float*)C1)[off] = acc[i][j][r];
          } else {  // OM == 3
            bf16 hb, lb; split1(acc[i][j][r], hb, lb);
            ((bf16*)C1)[off] = hb;
            ((bf16*)C2)[off] = lb;
          }
        }
      }
    }
  }
}

// ------------------------------------ split-precision flash attention -------
// grid (T/16, H); block = 4 waves; 16 q rows per block; the 4 waves split the
// key range (wave w takes 32-key tiles w, w+4, ...) with private (m,l,O),
// merged at the end via LDS. Heavy blocks (large qbase) dispatched first.
__launch_bounds__(256)
__global__ void k_attns(const bf16* __restrict__ Qh, const bf16* __restrict__ Ql,
                        const bf16* __restrict__ Kh, const bf16* __restrict__ Kl,
                        const bf16* __restrict__ Vh, const bf16* __restrict__ Vl,
                        bf16* __restrict__ Oh, bf16* __restrict__ Ol)
{
  const int tid = threadIdx.x;
  const int lane = tid & 63, wid = tid >> 6;
  const int head = blockIdx.y;
  const int qbase = (gridDim.x - 1 - blockIdx.x) * 16;
  const int lr = lane & 15, g = lane >> 4;

  __shared__ float o_l[4][16][132];
  __shared__ float m_l[4][16], l_l[4][16];
  // P-staging aliases o_l (o_l only written after a barrier post-loop)
  bf16* plbase = (bf16*)&o_l[0][0][0];
  bf16 (*pl_h)[40] = (bf16(*)[40])(plbase + wid * 16 * 40);
  bf16 (*pl_l)[40] = (bf16(*)[40])(plbase + (4 + wid) * 16 * 40);

  bf16x8 qfh[4], qfl[4];
  {
    size_t qoff = (size_t)(qbase + lr) * DD + head * HDIM;
#pragma unroll
    for (int c = 0; c < 4; ++c) {
      qfh[c] = *(const bf16x8*)(Qh + qoff + c * 32 + g * 8);
      qfl[c] = *(const bf16x8*)(Ql + qoff + c * 32 + g * 8);
    }
  }

  f32x4 o[8];
#pragma unroll
  for (int d = 0; d < 8; ++d) o[d] = (f32x4){0.f, 0.f, 0.f, 0.f};
  float m_r[4] = {-1e30f, -1e30f, -1e30f, -1e30f};
  float l_r[4] = {0.f, 0.f, 0.f, 0.f};

  const int qend = qbase + 16;
  for (int kb = wid * 32; kb < qend; kb += 128) {
    f32x4 s0 = {0.f,0.f,0.f,0.f}, s1 = {0.f,0.f,0.f,0.f};
    size_t k0off = (size_t)(kb + lr) * DD + head * HDIM;
    size_t k1off = k0off + (size_t)16 * DD;
#pragma unroll
    for (int c = 0; c < 4; ++c) {
      bf16x8 kh = *(const bf16x8*)(Kh + k0off + c * 32 + g * 8);
      bf16x8 kl = *(const bf16x8*)(Kl + k0off + c * 32 + g * 8);
      s0 = __builtin_amdgcn_mfma_f32_16x16x32_bf16(qfh[c], kh, s0, 0, 0, 0);
      s0 = __builtin_amdgcn_mfma_f32_16x16x32_bf16(qfh[c], kl, s0, 0, 0, 0);
      s0 = __builtin_amdgcn_mfma_f32_16x16x32_bf16(qfl[c], kh, s0, 0, 0, 0);
    }
#pragma unroll
    for (int c = 0; c < 4; ++c) {
      bf16x8 kh = *(const bf16x8*)(Kh + k1off + c * 32 + g * 8);
      bf16x8 kl = *(const bf16x8*)(Kl + k1off + c * 32 + g * 8);
      s1 = __builtin_amdgcn_mfma_f32_16x16x32_bf16(qfh[c], kh, s1, 0, 0, 0);
      s1 = __builtin_amdgcn_mfma_f32_16x16x32_bf16(qfh[c], kl, s1, 0, 0, 0);
      s1 = __builtin_amdgcn_mfma_f32_16x16x32_bf16(qfl[c], kh, s1, 0, 0, 0);
    }
    float p0[4], p1[4], mx[4], alpha[4];
#pragma unroll
    for (int r = 0; r < 4; ++r) {
      int q = qbase + g * 4 + r;
      float a0 = s0[r] * 0.08838834764831845f;
      float a1 = s1[r] * 0.08838834764831845f;
      if (kb + lr > q)      a0 = -1e30f;
      if (kb + 16 + lr > q) a1 = -1e30f;
      p0[r] = a0; p1[r] = a1;
      mx[r] = fmaxf(a0, a1);
    }
#pragma unroll
    for (int off = 1; off < 16; off <<= 1)
#pragma unroll
      for (int r = 0; r < 4; ++r) mx[r] = fmaxf(mx[r], __shfl_xor(mx[r], off, 64));
#pragma unroll
    for (int r = 0; r < 4; ++r) {
      float mn = fmaxf(m_r[r], mx[r]);
      alpha[r] = __expf(m_r[r] - mn);
      m_r[r] = mn;
      p0[r] = __expf(p0[r] - mn);
      p1[r] = __expf(p1[r] - mn);
    }
    float ps[4];
#pragma unroll
    for (int r = 0; r < 4; ++r) ps[r] = p0[r] + p1[r];
#pragma unroll
    for (int off = 1; off < 16; off <<= 1)
#pragma unroll
      for (int r = 0; r < 4; ++r) ps[r] += __shfl_xor(ps[r], off, 64);
#pragma unroll
    for (int r = 0; r < 4; ++r) l_r[r] = l_r[r] * alpha[r] + ps[r];
#pragma unroll
    for (int d = 0; d < 8; ++d)
#pragma unroll
      for (int r = 0; r < 4; ++r) o[d][r] *= alpha[r];
#pragma unroll
    for (int r = 0; r < 4; ++r) {
      bf16 hb, lb;
      split1(p0[r], hb, lb);
      pl_h[g * 4 + r][lr] = hb;
      pl_l[g * 4 + r][lr] = lb;
      split1(p1[r], hb, lb);
      pl_h[g * 4 + r][16 + lr] = hb;
      pl_l[g * 4 + r][16 + lr] = lb;
    }
    bf16x8 pah = *(const bf16x8*)&pl_h[lr][g * 8];
    bf16x8 pal = *(const bf16x8*)&pl_l[lr][g * 8];
#pragma unroll
    for (int d = 0; d < 8; ++d) {
      size_t voff = (size_t)(head * HDIM + d * 16 + lr) * TT + kb + g * 8;
      bf16x8 vfh = *(const bf16x8*)(Vh + voff);
      bf16x8 vfl = *(const bf16x8*)(Vl + voff);
      o[d] = __builtin_amdgcn_mfma_f32_16x16x32_bf16(pah, vfh, o[d], 0, 0, 0);
      o[d] = __builtin_amdgcn_mfma_f32_16x16x32_bf16(pah, vfl, o[d], 0, 0, 0);
      o[d] = __builtin_amdgcn_mfma_f32_16x16x32_bf16(pal, vfh, o[d], 0, 0, 0);
    }
  }

  __syncthreads();   // all waves done using P staging (aliases o_l)
  if (lr == 0) {
#pragma unroll
    for (int r = 0; r < 4; ++r) {
      m_l[wid][g * 4 + r] = m_r[r];
      l_l[wid][g * 4 + r] = l_r[r];
    }
  }
#pragma unroll
  for (int d = 0; d < 8; ++d)
#pragma unroll
    for (int r = 0; r < 4; ++r)
      o_l[wid][g * 4 + r][d * 16 + lr] = o[d][r];
  __syncthreads();

  // merge the 4 partials; thread -> (row, 8 cols)
  const int row = tid >> 4;
  const int c0 = (tid & 15) * 8;
  float m0v = m_l[0][row], m1v = m_l[1][row], m2v = m_l[2][row], m3v = m_l[3][row];
  float ms = fmaxf(fmaxf(m0v, m1v), fmaxf(m2v, m3v));
  float s0v = __expf(m0v - ms), s1v = __expf(m1v - ms);
  float s2v = __expf(m2v - ms), s3v = __expf(m3v - ms);
  float lsum = l_l[0][row] * s0v + l_l[1][row] * s1v
             + l_l[2][row] * s2v + l_l[3][row] * s3v;
  float inv = 1.f / lsum;
  union { bf16 b[8]; uint4 u; } ph, pl;
#pragma unroll
  for (int j = 0; j < 8; ++j) {
    float v = o_l[0][row][c0 + j] * s0v + o_l[1][row][c0 + j] * s1v
            + o_l[2][row][c0 + j] * s2v + o_l[3][row][c0 + j] * s3v;
    bf16 hb, lb;
    split1(v * inv, hb, lb);
    ph.b[j] = hb; pl.b[j] = lb;
  }
  size_t oi = (size_t)(qbase + row) * DD + head * HDIM + c0;
  *(uint4*)(Oh + oi) = ph.u;
  *(uint4*)(Ol + oi) = pl.u;
}

// ------------------------------------------------------------- helpers ------
__global__ void k_embed(const int* __restrict__ ids, const float* __restrict__ Em,
                        float* __restrict__ Hout)
{
  int t = blockIdx.x, tid = threadIdx.x;
  const float4* s = (const float4*)(Em + (size_t)ids[t] * DD);
  float4* dst = (float4*)(Hout + (size_t)t * DD);
  dst[tid] = s[tid];
  dst[tid + 256] = s[tid + 256];
}

template<bool ADDIN, bool WF32, bool FINAL>
__launch_bounds__(256)
__global__ void k_addrms(const float* __restrict__ Hin, float* __restrict__ Res,
                         const float* __restrict__ W,
                         bf16* __restrict__ Xh, bf16* __restrict__ Xl,
                         float* __restrict__ Xf)
{
  const int t = blockIdx.x, tid = threadIdx.x;
  const size_t base = (size_t)t * DD + tid * 8;
  float x[8];
  {
    const float4* hp = (const float4*)(Hin + base);
    float4 a = hp[0], b = hp[1];
    x[0]=a.x; x[1]=a.y; x[2]=a.z; x[3]=a.w;
    x[4]=b.x; x[5]=b.y; x[6]=b.z; x[7]=b.w;
    if (ADDIN) {
      const float4* rp = (const float4*)(Res + base);
      float4 c = rp[0], d = rp[1];
      x[0]+=c.x; x[1]+=c.y; x[2]+=c.z; x[3]+=c.w;
      x[4]+=d.x; x[5]+=d.y; x[6]+=d.z; x[7]+=d.w;
    }
  }
  {
    float4* rp = (float4*)(Res + base);
    rp[0] = make_float4(x[0], x[1], x[2], x[3]);
    rp[1] = make_float4(x[4], x[5], x[6], x[7]);
  }
  float ss = 0.f;
#pragma unroll
  for (int j = 0; j < 8; ++j) ss += x[j] * x[j];
#pragma unroll
  for (int off = 32; off; off >>= 1) ss += __shfl_xor(ss, off, 64);
  __shared__ float red[4];
  if ((tid & 63) == 0) red[tid >> 6] = ss;
  __syncthreads();
  float tot = red[0] + red[1] + red[2] + red[3];
  float sc = rsqrtf(tot * (1.0f / DD) + 1e-6f);
  float y[8];
#pragma unroll
  for (int j = 0; j < 8; ++j) y[j] = x[j] * sc * W[tid * 8 + j];
  if (!FINAL) {
    union { bf16 b[8]; uint4 u; } ph, pl;
#pragma unroll
    for (int j = 0; j < 8; ++j) { bf16 hb, lb; split1(y[j], hb, lb); ph.b[j] = hb; pl.b[j] = lb; }
    *(uint4*)(Xh + base) = ph.u;
    *(uint4*)(Xl + base) = pl.u;
  }
  if (WF32 || FINAL) {
    float4* xp = (float4*)(Xf + base);
    xp[0] = make_float4(y[0], y[1], y[2], y[3]);
    xp[1] = make_float4(y[4], y[5], y[6], y[7]);
  }
}

__global__ void k_rope2(bf16* __restrict__ Qh, bf16* __restrict__ Ql,
                        bf16* __restrict__ Kh, bf16* __restrict__ Kl,
                        const int* __restrict__ pos)
{
  int idx = blockIdx.x * 256 + threadIdx.x;
  int d = idx & 63;
  int h = (idx >> 6) & (HH - 1);
  int t = idx >> 10;
  if (t >= TT) return;
  double inv = pow(1.0e6, -(double)d / 64.0);
  double ang = (double)pos[t] * inv;
  double sd, cd;
  sincos(ang, &sd, &cd);
  float sn = (float)sd, cs = (float)cd;
  size_t base = (size_t)t * DD + h * HDIM + d;
  float q1 = (float)Qh[base] + (float)Ql[base];
  float q2 = (float)Qh[base + 64] + (float)Ql[base + 64];
  float qa = q1 * cs - q2 * sn, qb = q1 * sn + q2 * cs;
  bf16 hb, lb;
  split1(qa, hb, lb); Qh[base] = hb;      Ql[base] = lb;
  split1(qb, hb, lb); Qh[base + 64] = hb; Ql[base + 64] = lb;
  float k1 = (float)Kh[base] + (float)Kl[base];
  float k2 = (float)Kh[base + 64] + (float)Kl[base + 64];
  float ka = k1 * cs - k2 * sn, kb2 = k1 * sn + k2 * cs;
  split1(ka, hb, lb);  Kh[base] = hb;      Kl[base] = lb;
  split1(kb2, hb, lb); Kh[base + 64] = hb; Kl[base + 64] = lb;
}

__launch_bounds__(64)
__global__ void k_router(const float* __restrict__ Xf, const float* __restrict__ RW,
                         const float* __restrict__ SGW, int* __restrict__ eidx,
                         float* __restrict__ ew, float* __restrict__ sgate,
                         int* __restrict__ cnt)
{
  const int t = blockIdx.x, lane = threadIdx.x;
  const float* x = Xf + (size_t)t * DD;
  float acc[8] = {0,0,0,0,0,0,0,0};
  float sg = 0.f;
  for (int i = lane; i < DD; i += 64) {
    float xv = x[i];
    const float4* w = (const float4*)(RW + (size_t)i * NE);
    float4 w0 = w[0], w1 = w[1];
    acc[0] += xv * w0.x; acc[1] += xv * w0.y; acc[2] += xv * w0.z; acc[3] += xv * w0.w;
    acc[4] += xv * w1.x; acc[5] += xv * w1.y; acc[6] += xv * w1.z; acc[7] += xv * w1.w;
    sg += xv * SGW[i];
  }
#pragma unroll
  for (int off = 32; off; off >>= 1) {
#pragma unroll
    for (int e = 0; e < 8; ++e) acc[e] += __shfl_xor(acc[e], off, 64);
    sg += __shfl_xor(sg, off, 64);
  }
  if (lane == 0) {
    int i0 = 0; float v0 = acc[0];
    for (int e = 1; e < 8; ++e) if (acc[e] > v0) { v0 = acc[e]; i0 = e; }
    int i1 = -1; float v1 = -1e30f;
    for (int e = 0; e < 8; ++e) if (e != i0 && acc[e] > v1) { v1 = acc[e]; i1 = e; }
    float w0 = 1.f / (1.f + expf(v1 - v0));
    eidx[2*t] = i0; eidx[2*t+1] = i1;
    ew[2*t] = w0; ew[2*t+1] = 1.f - w0;
    sgate[t] = 1.f / (1.f + expf(-sg));
    atomicAdd(&cnt[i0], 1);
    atomicAdd(&cnt[i1], 1);
  }
}

__global__ void k_scan(const int* __restrict__ cnt, int* __restrict__ ofs)
{
  if (threadIdx.x == 0) {
    int s = 0;
    for (int e = 0; e < NE; ++e) { ofs[e] = s; s += cnt[e]; }
    ofs[NE] = s;
  }
}

__global__ void k_assign(const int* __restrict__ eidx, const int* __restrict__ ofs,
                         int* __restrict__ cursor, int* __restrict__ perm,
                         int* __restrict__ posof)
{
  int t = blockIdx.x * 256 + threadIdx.x;
  if (t >= TT) return;
#pragma unroll
  for (int j = 0; j < 2; ++j) {
    int e = eidx[2*t + j];
    int p = ofs[e] + atomicAdd(&cursor[e], 1);
    perm[p] = t;
    posof[2*t + j] = p;
  }
}

// silu(g)*u from f32 inputs -> bf16 hi/lo planes
__global__ void k_silup(const float* __restrict__ G, const float* __restrict__ U,
                        bf16* __restrict__ H, bf16* __restrict__ L)
{
  int i = (blockIdx.x * 256 + threadIdx.x) * 4;
  float4 g = *(const float4*)(G + i);
  float4 u = *(const float4*)(U + i);
  float s[4];
  s[0] = g.x / (1.f + expf(-g.x)) * u.x;
  s[1] = g.y / (1.f + expf(-g.y)) * u.y;
  s[2] = g.z / (1.f + expf(-g.z)) * u.z;
  s[3] = g.w / (1.f + expf(-g.w)) * u.w;
  bf16x4 h, l;
#pragma unroll
  for (int j = 0; j < 4; ++j) { bf16 hb, lb; split1(s[j], hb, lb); h[j] = hb; l[j] = lb; }
  *(bf16x4*)(H + i) = h;
  *(bf16x4*)(L + i) = l;
}

__global__ void k_combine(const float* __restrict__ Y, const float* __restrict__ SH,
                          const float* __restrict__ sgate, const float* __restrict__ ew,
                          const int* __restrict__ posof, float* __restrict__ Hout)
{
  int t = blockIdx.x, tid = threadIdx.x;
  int p0 = posof[2*t], p1 = posof[2*t+1];
  float w0 = ew[2*t], w1 = ew[2*t+1];
  float sgv = sgate[t];
  int d0 = tid * 8;
  const float4* a = (const float4*)(Y + (size_t)p0 * DD + d0);
  const float4* b = (const float4*)(Y + (size_t)p1 * DD + d0);
  float4 a0 = a[0], a1 = a[1], b0 = b[0], b1 = b[1];
  float y0[8] = {a0.x,a0.y,a0.z,a0.w,a1.x,a1.y,a1.z,a1.w};
  float y1[8] = {b0.x,b0.y,b0.z,b0.w,b1.x,b1.y,b1.z,b1.w};
  const float4* shp = (const float4*)(SH + (size_t)t * DD + d0);
  float4 sa = shp[0], sb = shp[1];
  float shv[8] = {sa.x, sa.y, sa.z, sa.w, sb.x, sb.y, sb.z, sb.w};
  float out[8];
#pragma unroll
  for (int j = 0; j < 8; ++j)
    out[j] = (y0[j] * w0 + y1[j] * w1 + sgv * shv[j]) * 0.70710678118654752f;
  float4* op = (float4*)(Hout + (size_t)t * DD + d0);
  op[0] = make_float4(out[0], out[1], out[2], out[3]);
  op[1] = make_float4(out[4], out[5], out[6], out[7]);
}

// -------------------------------------------------------------- driver ------
extern "C" void kernel_launch(void* const* d_in, const int* in_sizes, int n_in,
                              void* d_out, int out_size, void* d_ws, size_t ws_size,
                              hipStream_t stream)
{
  (void)in_sizes; (void)n_in; (void)out_size; (void)ws_size;
  const int*   ids  = (const int*)d_in[0];
  const int*   pos  = (const int*)d_in[1];
  const float* emb  = (const float*)d_in[2];
  const float* qw   = (const float*)d_in[3];
  const float* kw   = (const float*)d_in[4];
  const float* vw   = (const float*)d_in[5];
  const float* ow   = (const float*)d_in[6];
  const float* ln1  = (const float*)d_in[7];
  const float* ln2  = (const float*)d_in[8];
  const float* rw   = (const float*)d_in[9];
  const float* sgw  = (const float*)d_in[10];
  const float* wg   = (const float*)d_in[11];
  const float* wu   = (const float*)d_in[12];
  const float* wd   = (const float*)d_in[13];
  const float* swg  = (const float*)d_in[14];
  const float* swu  = (const float*)d_in[15];
  const float* swd  = (const float*)d_in[16];
  const float* fln  = (const float*)d_in[17];

  char* p = (char*)d_ws;
  auto alloc = [&](size_t b) { char* r = p; p += (b + 255) & ~(size_t)255; return r; };

  const size_t TD = (size_t)TT * DD;
  float* resid = (float*)alloc(TD * 4);
  float* hbuf  = (float*)alloc(TD * 4);
  float* xf    = (float*)alloc(TD * 4);
  bf16*  xh    = (bf16*) alloc(TD * 2);
  bf16*  xl    = (bf16*) alloc(TD * 2);
  bf16*  qhb   = (bf16*) alloc(TD * 2);
  bf16*  qlb   = (bf16*) alloc(TD * 2);
  bf16*  khb   = (bf16*) alloc(TD * 2);
  bf16*  klb   = (bf16*) alloc(TD * 2);
  bf16*  vth   = (bf16*) alloc(TD * 2);
  bf16*  vtl   = (bf16*) alloc(TD * 2);
  bf16*  aoh   = (bf16*) alloc(TD * 2);
  bf16*  aol   = (bf16*) alloc(TD * 2);
  float* shb   = (float*)alloc(TD * 4);
  const size_t SGF = (size_t)TT * FSS;
  const size_t GEF = (size_t)TT * TOPK * FF;
  bf16*  shph  = (bf16*) alloc(SGF * 2);
  bf16*  shpl  = (bf16*) alloc(SGF * 2);
  bf16*  geph  = (bf16*) alloc(GEF * 2);
  bf16*  gepl  = (bf16*) alloc(GEF * 2);
  float* region = (float*)alloc(2 * SGF * 4);
  float* sgbf = region;
  float* subf = region + SGF;
  float* gebf = region;
  float* uebf = region + GEF;
  float* ybf  = region + 2 * GEF;
  const size_t WME = (size_t)NE * DD * FF;
  bf16* wbh = (bf16*)alloc(WME * 2);
  bf16* wbl = (bf16*)alloc(WME * 2);
  int*   eidx  = (int*)  alloc((size_t)TT * TOPK * 4);
  float* ewb   = (float*)alloc((size_t)TT * TOPK * 4);
  float* sgate = (float*)alloc((size_t)TT * 4);
  int*   perm  = (int*)  alloc((size_t)TT * TOPK * 4);
  int*   posof = (int*)  alloc((size_t)TT * TOPK * 4);
  int*   cnt   = (int*)  alloc(64);
  int*   ofs   = (int*)  alloc(64);
  int*   cursor = cnt + 8;

  k_embed<<<TT, 256, 0, stream>>>(ids, emb, hbuf);

  for (int l = 0; l < NL; ++l) {
    const float* qw_l  = qw  + (size_t)l * DD * DD;
    const float* kw_l  = kw  + (size_t)l * DD * DD;
    const float* vw_l  = vw  + (size_t)l * DD * DD;
    const float* ow_l  = ow  + (size_t)l * DD * DD;
    const float* ln1_l = ln1 + (size_t)l * DD;
    const float* ln2_l = ln2 + (size_t)l * DD;
    const float* rw_l  = rw  + (size_t)l * DD * NE;
    const float* sgw_l = sgw + (size_t)l * DD;
    const float* wg_l  = wg  + (size_t)l * NE * DD * FF;
    const float* wu_l  = wu  + (size_t)l * NE * DD * FF;
    const float* wd_l  = wd  + (size_t)l * NE * FF * DD;
    const float* swg_l = swg + (size_t)l * DD * FSS;
    const float* swu_l = swu + (size_t)l * DD * FSS;
    const float* swd_l = swd + (size_t)l * FSS * DD;
    const bool last = (l == NL - 1);

    if (l == 0)
      k_addrms<false,false,false><<<TT,256,0,stream>>>(hbuf, resid, ln1_l, xh, xl, nullptr);
    else
      k_addrms<true, false,false><<<TT,256,0,stream>>>(hbuf, resid, ln1_l, xh, xl, nullptr);

    // ---- attention (split everywhere: feeds this layer's ln2 -> router) ----
    k_wtrans<true><<<dim3(32,32),256,0,stream>>>(qw_l, wbh, wbl, DD, DD);
    k_gemmp<64,3,false,false,3><<<dim3(32,16),256,0,stream>>>(xh, xl, wbh, wbl, qhb, qlb, TT, DD, DD, DD, DD, nullptr,nullptr,nullptr);
    k_wtrans<true><<<dim3(32,32),256,0,stream>>>(kw_l, wbh, wbl, DD, DD);
    k_gemmp<64,3,false,false,3><<<dim3(32,16),256,0,stream>>>(xh, xl, wbh, wbl, khb, klb, TT, DD, DD, DD, DD, nullptr,nullptr,nullptr);
    k_wtrans<true><<<dim3(32,32),256,0,stream>>>(vw_l, wbh, wbl, DD, DD);
    k_gemmp<64,3,false,false,4><<<dim3(32,16),256,0,stream>>>(xh, xl, wbh, wbl, vth, vtl, TT, DD, DD, DD, TT, nullptr,nullptr,nullptr);
    k_rope2<<<(TT*HH*64)/256, 256, 0, stream>>>(qhb, qlb, khb, klb, pos);
    k_attns<<<dim3(TT/16, HH), 256, 0, stream>>>(qhb, qlb, khb, klb, vth, vtl, aoh, aol);
    k_wtrans<true><<<dim3(32,32),256,0,stream>>>(ow_l, wbh, wbl, DD, DD);
    k_gemmp<64,3,false,false,1><<<dim3(32,16),256,0,stream>>>(aoh, aol, wbh, wbl, hbuf, nullptr, TT, DD, DD, DD, DD, nullptr,nullptr,nullptr);

    k_addrms<true,true,false><<<TT,256,0,stream>>>(hbuf, resid, ln2_l, xh, xl, xf);

    hipMemsetAsync(cnt, 0, 64, stream);
    k_router<<<TT, 64, 0, stream>>>(xf, rw_l, sgw_l, eidx, ewb, sgate, cnt);
    k_scan<<<1, 64, 0, stream>>>(cnt, ofs);
    k_assign<<<TT/256, 256, 0, stream>>>(eidx, ofs, cursor, perm, posof);

    // ---- shared expert ----
    if (!last) {
      k_wtrans<true><<<dim3(32,88),256,0,stream>>>(swg_l, wbh, wbl, DD, FSS);
      k_gemmp<128,3,false,false,1><<<dim3(16,44),256,0,stream>>>(xh, xl, wbh, wbl, sgbf, nullptr, TT, FSS, DD, DD, FSS, nullptr,nullptr,nullptr);
      k_wtrans<true><<<dim3(32,88),256,0,stream>>>(swu_l, wbh, wbl, DD, FSS);
      k_gemmp<128,3,false,false,1><<<dim3(16,44),256,0,stream>>>(xh, xl, wbh, wbl, subf, nullptr, TT, FSS, DD, DD, FSS, nullptr,nullptr,nullptr);
      k_silup<<<(TT*FSS/4)/256, 256, 0, stream>>>(sgbf, subf, shph, shpl);
      k_wtrans<true><<<dim3(88,32),256,0,stream>>>(swd_l, wbh, wbl, FSS, DD);
      k_gemmp<64,3,false,false,1><<<dim3(32,16),256,0,stream>>>(shph, shpl, wbh, wbl, shb, nullptr, TT, DD, FSS, FSS, DD, nullptr,nullptr,nullptr);
    } else {
      k_wtrans<false><<<dim3(32,88),256,0,stream>>>(swg_l, wbh, wbl, DD, FSS);
      k_gemmp<128,1,false,false,1><<<dim3(16,44),256,0,stream>>>(xh, xl, wbh, wbl, sgbf, nullptr, TT, FSS, DD, DD, FSS, nullptr,nullptr,nullptr);
      k_wtrans<false><<<dim3(32,88),256,0,stream>>>(swu_l, wbh, wbl, DD, FSS);
      k_gemmp<128,1,false,false,1><<<dim3(16,44),256,0,stream>>>(xh, xl, wbh, wbl, subf, nullptr, TT, FSS, DD, DD, FSS, nullptr,nullptr,nullptr);
      k_silup<<<(TT*FSS/4)/256, 256, 0, stream>>>(sgbf, subf, shph, shpl);
      k_wtrans<false><<<dim3(88,32),256,0,stream>>>(swd_l, wbh, wbl, FSS, DD);
      k_gemmp<64,1,false,false,1><<<dim3(32,16),256,0,stream>>>(shph, shpl, wbh, wbl, shb, nullptr, TT, DD, FSS, FSS, DD, nullptr,nullptr,nullptr);
    }

    // ---- routed experts ----
    if (!last) {
      k_wtrans<true><<<dim3(32,22,NE),256,0,stream>>>(wg_l, wbh, wbl, DD, FF);
      k_gemmp<64,3,true,true,1><<<dim3(64,11,NE),256,0,stream>>>(xh, xl, wbh, wbl, gebf, nullptr, TT, FF, DD, DD, FF, perm, cnt, ofs);
      k_wtrans<true><<<dim3(32,22,NE),256,0,stream>>>(wu_l, wbh, wbl, DD, FF);
      k_gemmp<64,3,true,true,1><<<dim3(64,11,NE),256,0,stream>>>(xh, xl, wbh, wbl, uebf, nullptr, TT, FF, DD, DD, FF, perm, cnt, ofs);
      k_silup<<<(GEF/4)/256, 256, 0, stream>>>(gebf, uebf, geph, gepl);
      k_wtrans<true><<<dim3(22,32,NE),256,0,stream>>>(wd_l, wbh, wbl, FF, DD);
      k_gemmp<64,3,true,false,1><<<dim3(64,16,NE),256,0,stream>>>(geph, gepl, wbh, wbl, ybf, nullptr, TT, DD, FF, FF, DD, nullptr, cnt, ofs);
    } else {
      k_wtrans<false><<<dim3(32,22,NE),256,0,stream>>>(wg_l, wbh, wbl, DD, FF);
      k_gemmp<64,1,true,true,1><<<dim3(64,11,NE),256,0,stream>>>(xh, xl, wbh, wbl, gebf, nullptr, TT, FF, DD, DD, FF, perm, cnt, ofs);
      k_wtrans<false><<<dim3(32,22,NE),256,0,stream>>>(wu_l, wbh, wbl, DD, FF);
      k_gemmp<64,1,true,true,1><<<dim3(64,11,NE),256,0,stream>>>(xh, xl, wbh, wbl, uebf, nullptr, TT, FF, DD, DD, FF, perm, cnt, ofs);
      k_silup<<<(GEF/4)/256, 256, 0, stream>>>(gebf, uebf, geph, gepl);
      k_wtrans<false><<<dim3(22,32,NE),256,0,stream>>>(wd_l, wbh, wbl, FF, DD);
      k_gemmp<64,1,true,false,1><<<dim3(64,16,NE),256,0,stream>>>(geph, gepl, wbh, wbl, ybf, nullptr, TT, DD, FF, FF, DD, nullptr, cnt, ofs);
    }
    k_combine<<<TT, 256, 0, stream>>>(ybf, shb, sgate, ewb, posof, hbuf);
  }

  k_addrms<true,false,true><<<TT,256,0,stream>>>(hbuf, resid, fln, nullptr, nullptr, (float*)d_out);
}